// Round 1
// baseline (454.515 us; speedup 1.0000x reference)
//
#include <hip/hip_runtime.h>
#include <math.h>

// ---------------------------------------------------------------------------
// GAT 2-layer forward, N=50000, E=800000 (+N self loops), EMB=128,
// layer1: heads=8, C=16 (concat -> 128), layer2: heads=1, C=64.
// Strategy: CSR-by-dst build per call (hist/scan/scatter), fused GEMM+alpha
// epilogues, one gather pass per layer (no float atomics), softmax without
// max-subtraction (shift-invariant; logits are O(1)).
// ---------------------------------------------------------------------------

__global__ __launch_bounds__(256) void hist_kernel(const int* __restrict__ dst, int E,
                                                   int* __restrict__ deg) {
    int i = blockIdx.x * 256 + threadIdx.x;
    if (i < E) atomicAdd(&deg[dst[i]], 1);
}

// block-level exclusive scan (256 elems/block); writes per-block exclusive
// prefix into rowstart and the block total into blocksum[blockIdx].
__global__ __launch_bounds__(256) void scan1_kernel(const int* __restrict__ deg, int N,
                                                    int* __restrict__ rowstart,
                                                    int* __restrict__ blocksum) {
    __shared__ int tmp[256];
    int t = threadIdx.x;
    int i = blockIdx.x * 256 + t;
    int v = (i < N) ? deg[i] : 0;
    tmp[t] = v;
    __syncthreads();
    for (int off = 1; off < 256; off <<= 1) {
        int x = (t >= off) ? tmp[t - off] : 0;
        __syncthreads();
        tmp[t] += x;
        __syncthreads();
    }
    if (i < N) rowstart[i] = tmp[t] - v;            // exclusive within block
    if (t == 255) blocksum[blockIdx.x] = tmp[t];    // block total
}

// exclusive scan of the (<=256) block sums, in place.
__global__ __launch_bounds__(256) void scan2_kernel(int* __restrict__ blocksum, int nb) {
    __shared__ int tmp[256];
    int t = threadIdx.x;
    int v = (t < nb) ? blocksum[t] : 0;
    tmp[t] = v;
    __syncthreads();
    for (int off = 1; off < 256; off <<= 1) {
        int x = (t >= off) ? tmp[t - off] : 0;
        __syncthreads();
        tmp[t] += x;
        __syncthreads();
    }
    if (t < nb) blocksum[t] = tmp[t] - v;
}

__global__ __launch_bounds__(256) void scan3_kernel(int* __restrict__ rowstart,
                                                    const int* __restrict__ blockoff,
                                                    int N, int E) {
    int i = blockIdx.x * 256 + threadIdx.x;
    if (i < N) rowstart[i] += blockoff[i >> 8];
    else if (i == N) rowstart[N] = E;
}

__global__ __launch_bounds__(256) void scatter_kernel(const int* __restrict__ src,
                                                      const int* __restrict__ dst, int E,
                                                      const int* __restrict__ rowstart,
                                                      int* __restrict__ cursor,
                                                      int* __restrict__ esrc) {
    int i = blockIdx.x * 256 + threadIdx.x;
    if (i < E) {
        int d = dst[i];
        int p = atomicAdd(&cursor[d], 1);
        esrc[rowstart[d] + p] = src[i];
    }
}

// GEMM1: h1[N,128] = x[N,128] @ W1[128,128]; epilogue computes per-head
// attention dots alpha_s/alpha_d (thread g owns head g's 16 cols).
__global__ __launch_bounds__(256) void gemm1_kernel(const float* __restrict__ x,
                                                    const float* __restrict__ W,
                                                    const float* __restrict__ a_s,
                                                    const float* __restrict__ a_d,
                                                    float* __restrict__ h1,
                                                    float* __restrict__ als,
                                                    float* __restrict__ ald, int N) {
    __shared__ float Xs[32 * 128];  // 16 KB
    __shared__ float Ws[32 * 128];  // 16 KB (K-tile of W)
    int t = threadIdx.x;
    int row0 = blockIdx.x * 32;
    {
        const float4* xv = (const float4*)(x + (size_t)row0 * 128);
        float4* Xv = (float4*)Xs;
        int valid = (N - row0) * 32;  // float4s per 32-row tile actually present
        for (int i = t; i < 1024; i += 256)
            Xv[i] = (i < valid) ? xv[i] : make_float4(0.f, 0.f, 0.f, 0.f);
    }
    int r = t >> 3, g = t & 7;
    float acc[16];
#pragma unroll
    for (int j = 0; j < 16; j++) acc[j] = 0.f;

    for (int kt = 0; kt < 4; kt++) {
        __syncthreads();
        {
            const float4* wv = (const float4*)(W + (size_t)kt * 32 * 128);
            float4* Wv = (float4*)Ws;
            for (int i = t; i < 1024; i += 256) Wv[i] = wv[i];
        }
        __syncthreads();
        const float* xr = Xs + r * 128 + kt * 32;
#pragma unroll 4
        for (int kk = 0; kk < 32; kk++) {
            float xv = xr[kk];
            const float4* wr = (const float4*)(Ws + kk * 128 + g * 16);
            float4 w0 = wr[0], w1 = wr[1], w2 = wr[2], w3 = wr[3];
            acc[0] += xv * w0.x;  acc[1] += xv * w0.y;
            acc[2] += xv * w0.z;  acc[3] += xv * w0.w;
            acc[4] += xv * w1.x;  acc[5] += xv * w1.y;
            acc[6] += xv * w1.z;  acc[7] += xv * w1.w;
            acc[8] += xv * w2.x;  acc[9] += xv * w2.y;
            acc[10] += xv * w2.z; acc[11] += xv * w2.w;
            acc[12] += xv * w3.x; acc[13] += xv * w3.y;
            acc[14] += xv * w3.z; acc[15] += xv * w3.w;
        }
    }
    int n = row0 + r;
    if (n < N) {
        float4* o = (float4*)(h1 + (size_t)n * 128 + g * 16);
        o[0] = make_float4(acc[0], acc[1], acc[2], acc[3]);
        o[1] = make_float4(acc[4], acc[5], acc[6], acc[7]);
        o[2] = make_float4(acc[8], acc[9], acc[10], acc[11]);
        o[3] = make_float4(acc[12], acc[13], acc[14], acc[15]);
        float ds = 0.f, dd = 0.f;
        const float* As = a_s + g * 16;
        const float* Ad = a_d + g * 16;
#pragma unroll
        for (int j = 0; j < 16; j++) {
            ds += acc[j] * As[j];
            dd += acc[j] * Ad[j];
        }
        als[n * 8 + g] = ds;
        ald[n * 8 + g] = dd;
    }
}

// Aggregation layer 1: one 64-lane wave per destination node; lane owns
// channels (2*lane, 2*lane+1) -> head = lane>>3. Softmax denominator inline.
// Epilogue: +b1, ELU, store act1.
__global__ __launch_bounds__(256) void agg1_kernel(const float* __restrict__ h1,
                                                   const float* __restrict__ als,
                                                   const float* __restrict__ ald,
                                                   const int* __restrict__ rowstart,
                                                   const int* __restrict__ esrc,
                                                   const float* __restrict__ b1,
                                                   float* __restrict__ act1, int N) {
    int gtid = blockIdx.x * blockDim.x + threadIdx.x;
    int n = gtid >> 6;
    if (n >= N) return;
    int lane = threadIdx.x & 63;
    int head = lane >> 3;
    float adv = ald[n * 8 + head];
    float accx = 0.f, accy = 0.f, wsum = 0.f;
    int beg = rowstart[n], end = rowstart[n + 1];
    for (int j = beg; j < end; j++) {
        int s = esrc[j];
        float e = als[s * 8 + head] + adv;
        e = (e > 0.f) ? e : 0.2f * e;
        float w = __expf(e);
        wsum += w;
        const float2 hv = *(const float2*)(h1 + (size_t)s * 128 + lane * 2);
        accx += w * hv.x;
        accy += w * hv.y;
    }
    {  // self loop
        float e = als[n * 8 + head] + adv;
        e = (e > 0.f) ? e : 0.2f * e;
        float w = __expf(e);
        wsum += w;
        const float2 hv = *(const float2*)(h1 + (size_t)n * 128 + lane * 2);
        accx += w * hv.x;
        accy += w * hv.y;
    }
    float inv = 1.f / (wsum + 1e-16f);
    float o0 = accx * inv + b1[lane * 2];
    float o1 = accy * inv + b1[lane * 2 + 1];
    o0 = (o0 > 0.f) ? o0 : (__expf(o0) - 1.f);  // ELU
    o1 = (o1 > 0.f) ? o1 : (__expf(o1) - 1.f);
    *(float2*)(act1 + (size_t)n * 128 + lane * 2) = make_float2(o0, o1);
}

// GEMM2: h2[N,64] = act1[N,128] @ W2[128,64]; epilogue computes scalar
// alpha2_s/alpha2_d per node via 8-lane shuffle reduction.
__global__ __launch_bounds__(256) void gemm2_kernel(const float* __restrict__ act1,
                                                    const float* __restrict__ W2,
                                                    const float* __restrict__ a2s,
                                                    const float* __restrict__ a2d,
                                                    float* __restrict__ h2,
                                                    float* __restrict__ al2s,
                                                    float* __restrict__ al2d, int N) {
    __shared__ float Ws[128 * 64];  // 32 KB (whole W2)
    __shared__ float Xs[32 * 128];  // 16 KB
    int t = threadIdx.x;
    int row0 = blockIdx.x * 32;
    {
        const float4* wv = (const float4*)W2;
        float4* Wv = (float4*)Ws;
        for (int i = t; i < 2048; i += 256) Wv[i] = wv[i];
    }
    {
        const float4* xv = (const float4*)(act1 + (size_t)row0 * 128);
        float4* Xv = (float4*)Xs;
        int valid = (N - row0) * 32;
        for (int i = t; i < 1024; i += 256)
            Xv[i] = (i < valid) ? xv[i] : make_float4(0.f, 0.f, 0.f, 0.f);
    }
    __syncthreads();
    int r = t >> 3, g = t & 7;  // 8 cols per thread: cols 8g..8g+7
    float acc[8];
#pragma unroll
    for (int j = 0; j < 8; j++) acc[j] = 0.f;
    const float* xr = Xs + r * 128;
#pragma unroll 4
    for (int k = 0; k < 128; k++) {
        float xv = xr[k];
        const float4* wr = (const float4*)(Ws + k * 64 + g * 8);
        float4 w0 = wr[0], w1 = wr[1];
        acc[0] += xv * w0.x; acc[1] += xv * w0.y;
        acc[2] += xv * w0.z; acc[3] += xv * w0.w;
        acc[4] += xv * w1.x; acc[5] += xv * w1.y;
        acc[6] += xv * w1.z; acc[7] += xv * w1.w;
    }
    float ps = 0.f, pd = 0.f;
#pragma unroll
    for (int j = 0; j < 8; j++) {
        ps += acc[j] * a2s[g * 8 + j];
        pd += acc[j] * a2d[g * 8 + j];
    }
#pragma unroll
    for (int off = 1; off < 8; off <<= 1) {  // reduce across the 8 g-lanes
        ps += __shfl_xor(ps, off, 64);
        pd += __shfl_xor(pd, off, 64);
    }
    int n = row0 + r;
    if (n < N) {
        float4* o = (float4*)(h2 + (size_t)n * 64 + g * 8);
        o[0] = make_float4(acc[0], acc[1], acc[2], acc[3]);
        o[1] = make_float4(acc[4], acc[5], acc[6], acc[7]);
        if (g == 0) {
            al2s[n] = ps;
            al2d[n] = pd;
        }
    }
}

// Aggregation layer 2: wave per node, lane owns channel lane (C=64, 1 head).
// Epilogue: +b2, store final output.
__global__ __launch_bounds__(256) void agg2_kernel(const float* __restrict__ h2,
                                                   const float* __restrict__ al2s,
                                                   const float* __restrict__ al2d,
                                                   const int* __restrict__ rowstart,
                                                   const int* __restrict__ esrc,
                                                   const float* __restrict__ b2,
                                                   float* __restrict__ out, int N) {
    int gtid = blockIdx.x * blockDim.x + threadIdx.x;
    int n = gtid >> 6;
    if (n >= N) return;
    int lane = threadIdx.x & 63;
    float adv = al2d[n];
    float acc = 0.f, wsum = 0.f;
    int beg = rowstart[n], end = rowstart[n + 1];
    for (int j = beg; j < end; j++) {
        int s = esrc[j];
        float e = al2s[s] + adv;
        e = (e > 0.f) ? e : 0.2f * e;
        float w = __expf(e);
        wsum += w;
        acc += w * h2[(size_t)s * 64 + lane];
    }
    {  // self loop
        float e = al2s[n] + adv;
        e = (e > 0.f) ? e : 0.2f * e;
        float w = __expf(e);
        wsum += w;
        acc += w * h2[(size_t)n * 64 + lane];
    }
    out[(size_t)n * 64 + lane] = acc / (wsum + 1e-16f) + b2[lane];
}

extern "C" void kernel_launch(void* const* d_in, const int* in_sizes, int n_in,
                              void* d_out, int out_size, void* d_ws, size_t ws_size,
                              hipStream_t stream) {
    (void)n_in; (void)out_size; (void)ws_size;
    const float* x   = (const float*)d_in[0];
    const int*   ei  = (const int*)d_in[1];
    const float* W1  = (const float*)d_in[2];
    const float* a1s = (const float*)d_in[3];
    const float* a1d = (const float*)d_in[4];
    const float* b1  = (const float*)d_in[5];
    const float* W2  = (const float*)d_in[6];
    const float* a2s = (const float*)d_in[7];
    const float* a2d = (const float*)d_in[8];
    const float* b2  = (const float*)d_in[9];
    float* out = (float*)d_out;

    const int N = in_sizes[0] / 128;
    const int E = in_sizes[1] / 2;
    const int* src = ei;
    const int* dst = ei + E;

    // workspace carve-up (256B-aligned regions)
    char* wp = (char*)d_ws;
    auto alloc = [&](size_t bytes) -> void* {
        void* p = (void*)wp;
        wp += (bytes + 255) & ~(size_t)255;
        return p;
    };
    float* h1   = (float*)alloc((size_t)N * 128 * 4);
    float* act1 = (float*)alloc((size_t)N * 128 * 4);
    float* h2   = (float*)alloc((size_t)N * 64 * 4);
    float* al1s = (float*)alloc((size_t)N * 8 * 4);
    float* al1d = (float*)alloc((size_t)N * 8 * 4);
    float* al2s = (float*)alloc((size_t)N * 4);
    float* al2d = (float*)alloc((size_t)N * 4);
    int* deg      = (int*)alloc((size_t)N * 4);
    int* rowstart = (int*)alloc((size_t)(N + 1) * 4);
    int* cursor   = (int*)alloc((size_t)N * 4);
    int* esrc     = (int*)alloc((size_t)E * 4);
    int* blocksum = (int*)alloc(256 * 4);

    const int nbScan = (N + 255) / 256;           // 196 for N=50000 (<=256 req'd)
    const int gridE  = (E + 255) / 256;
    const int gridN1 = (N + 31) / 32;             // GEMM tiles
    const int gridAgg = (N * 64 + 255) / 256;     // wave per node

    hipMemsetAsync(deg, 0, (size_t)N * 4, stream);
    hipMemsetAsync(cursor, 0, (size_t)N * 4, stream);

    hist_kernel<<<gridE, 256, 0, stream>>>(dst, E, deg);
    scan1_kernel<<<nbScan, 256, 0, stream>>>(deg, N, rowstart, blocksum);
    scan2_kernel<<<1, 256, 0, stream>>>(blocksum, nbScan);
    scan3_kernel<<<(N + 256) / 256, 256, 0, stream>>>(rowstart, blocksum, N, E);
    scatter_kernel<<<gridE, 256, 0, stream>>>(src, dst, E, rowstart, cursor, esrc);

    gemm1_kernel<<<gridN1, 256, 0, stream>>>(x, W1, a1s, a1d, h1, al1s, al1d, N);
    agg1_kernel<<<gridAgg, 256, 0, stream>>>(h1, al1s, al1d, rowstart, esrc, b1, act1, N);
    gemm2_kernel<<<gridN1, 256, 0, stream>>>(act1, W2, a2s, a2d, h2, al2s, al2d, N);
    agg2_kernel<<<gridAgg, 256, 0, stream>>>(h2, al2s, al2d, rowstart, esrc, b2, out, N);
}

// Round 2
// 439.342 us; speedup vs baseline: 1.0345x; 1.0345x over previous
//
#include <hip/hip_runtime.h>
#include <hip/hip_fp16.h>
#include <math.h>

// ---------------------------------------------------------------------------
// GAT 2-layer forward, N=50000, E=800000 (+N self loops), EMB=128,
// layer1: heads=8, C=16 (concat -> 128), layer2: heads=1, C=64.
// CSR-by-dst build per call, fused GEMM+alpha epilogues, one gather pass per
// layer (no float atomics), softmax without max-subtraction.
// R1: h1/h2 stored as fp16 to halve the dominant gather traffic (agg1/agg2);
//     logits + accumulation stay fp32. cursor init fused into scan3.
// ---------------------------------------------------------------------------

__global__ __launch_bounds__(256) void hist_kernel(const int* __restrict__ dst, int E,
                                                   int* __restrict__ deg) {
    int i = blockIdx.x * 256 + threadIdx.x;
    if (i < E) atomicAdd(&deg[dst[i]], 1);
}

__global__ __launch_bounds__(256) void scan1_kernel(const int* __restrict__ deg, int N,
                                                    int* __restrict__ rowstart,
                                                    int* __restrict__ blocksum) {
    __shared__ int tmp[256];
    int t = threadIdx.x;
    int i = blockIdx.x * 256 + t;
    int v = (i < N) ? deg[i] : 0;
    tmp[t] = v;
    __syncthreads();
    for (int off = 1; off < 256; off <<= 1) {
        int x = (t >= off) ? tmp[t - off] : 0;
        __syncthreads();
        tmp[t] += x;
        __syncthreads();
    }
    if (i < N) rowstart[i] = tmp[t] - v;
    if (t == 255) blocksum[blockIdx.x] = tmp[t];
}

__global__ __launch_bounds__(256) void scan2_kernel(int* __restrict__ blocksum, int nb) {
    __shared__ int tmp[256];
    int t = threadIdx.x;
    int v = (t < nb) ? blocksum[t] : 0;
    tmp[t] = v;
    __syncthreads();
    for (int off = 1; off < 256; off <<= 1) {
        int x = (t >= off) ? tmp[t - off] : 0;
        __syncthreads();
        tmp[t] += x;
        __syncthreads();
    }
    if (t < nb) blocksum[t] = tmp[t] - v;
}

// adds block offsets; also initializes cursor[i] = rowstart[i] for scatter.
__global__ __launch_bounds__(256) void scan3_kernel(int* __restrict__ rowstart,
                                                    const int* __restrict__ blockoff,
                                                    int* __restrict__ cursor,
                                                    int N, int E) {
    int i = blockIdx.x * 256 + threadIdx.x;
    if (i < N) {
        int v = rowstart[i] + blockoff[i >> 8];
        rowstart[i] = v;
        cursor[i] = v;
    } else if (i == N) {
        rowstart[N] = E;
    }
}

__global__ __launch_bounds__(256) void scatter_kernel(const int* __restrict__ src,
                                                      const int* __restrict__ dst, int E,
                                                      int* __restrict__ cursor,
                                                      int* __restrict__ esrc) {
    int i = blockIdx.x * 256 + threadIdx.x;
    if (i < E) {
        int p = atomicAdd(&cursor[dst[i]], 1);
        esrc[p] = src[i];
    }
}

// GEMM1: h1[N,128] = x[N,128] @ W1[128,128] (fp16 out); epilogue computes
// per-head attention dots alpha_s/alpha_d in fp32 (thread g owns head g).
__global__ __launch_bounds__(256) void gemm1_kernel(const float* __restrict__ x,
                                                    const float* __restrict__ W,
                                                    const float* __restrict__ a_s,
                                                    const float* __restrict__ a_d,
                                                    __half* __restrict__ h1,
                                                    float* __restrict__ als,
                                                    float* __restrict__ ald, int N) {
    __shared__ float Xs[32 * 128];
    __shared__ float Ws[32 * 128];
    int t = threadIdx.x;
    int row0 = blockIdx.x * 32;
    {
        const float4* xv = (const float4*)(x + (size_t)row0 * 128);
        float4* Xv = (float4*)Xs;
        int valid = (N - row0) * 32;
        for (int i = t; i < 1024; i += 256)
            Xv[i] = (i < valid) ? xv[i] : make_float4(0.f, 0.f, 0.f, 0.f);
    }
    int r = t >> 3, g = t & 7;
    float acc[16];
#pragma unroll
    for (int j = 0; j < 16; j++) acc[j] = 0.f;

    for (int kt = 0; kt < 4; kt++) {
        __syncthreads();
        {
            const float4* wv = (const float4*)(W + (size_t)kt * 32 * 128);
            float4* Wv = (float4*)Ws;
            for (int i = t; i < 1024; i += 256) Wv[i] = wv[i];
        }
        __syncthreads();
        const float* xr = Xs + r * 128 + kt * 32;
#pragma unroll 4
        for (int kk = 0; kk < 32; kk++) {
            float xv = xr[kk];
            const float4* wr = (const float4*)(Ws + kk * 128 + g * 16);
            float4 w0 = wr[0], w1 = wr[1], w2 = wr[2], w3 = wr[3];
            acc[0] += xv * w0.x;  acc[1] += xv * w0.y;
            acc[2] += xv * w0.z;  acc[3] += xv * w0.w;
            acc[4] += xv * w1.x;  acc[5] += xv * w1.y;
            acc[6] += xv * w1.z;  acc[7] += xv * w1.w;
            acc[8] += xv * w2.x;  acc[9] += xv * w2.y;
            acc[10] += xv * w2.z; acc[11] += xv * w2.w;
            acc[12] += xv * w3.x; acc[13] += xv * w3.y;
            acc[14] += xv * w3.z; acc[15] += xv * w3.w;
        }
    }
    int n = row0 + r;
    if (n < N) {
        __align__(16) __half2 hv[8];
#pragma unroll
        for (int j = 0; j < 8; j++)
            hv[j] = __floats2half2_rn(acc[2 * j], acc[2 * j + 1]);
        float4* o = (float4*)(h1 + (size_t)n * 128 + g * 16);
        o[0] = *(float4*)&hv[0];
        o[1] = *(float4*)&hv[4];
        float ds = 0.f, dd = 0.f;
        const float* As = a_s + g * 16;
        const float* Ad = a_d + g * 16;
#pragma unroll
        for (int j = 0; j < 16; j++) {
            ds += acc[j] * As[j];
            dd += acc[j] * Ad[j];
        }
        als[n * 8 + g] = ds;
        ald[n * 8 + g] = dd;
    }
}

// Aggregation layer 1: one wave per dst node; lane owns channels
// (2*lane, 2*lane+1) -> head = lane>>3. fp16 row gather, fp32 accumulate.
// Epilogue: +b1, ELU, store act1 (fp32).
__global__ __launch_bounds__(256) void agg1_kernel(const __half* __restrict__ h1,
                                                   const float* __restrict__ als,
                                                   const float* __restrict__ ald,
                                                   const int* __restrict__ rowstart,
                                                   const int* __restrict__ esrc,
                                                   const float* __restrict__ b1,
                                                   float* __restrict__ act1, int N) {
    int gtid = blockIdx.x * blockDim.x + threadIdx.x;
    int n = gtid >> 6;
    if (n >= N) return;
    int lane = threadIdx.x & 63;
    int head = lane >> 3;
    const __half2* h1v = (const __half2*)h1;  // stride 64 per row
    float adv = ald[n * 8 + head];
    float accx = 0.f, accy = 0.f, wsum = 0.f;
    int beg = rowstart[n], end = rowstart[n + 1];
    for (int j = beg; j < end; j++) {
        int s = esrc[j];
        float e = als[s * 8 + head] + adv;
        e = (e > 0.f) ? e : 0.2f * e;
        float w = __expf(e);
        wsum += w;
        float2 hv = __half22float2(h1v[(size_t)s * 64 + lane]);
        accx += w * hv.x;
        accy += w * hv.y;
    }
    {  // self loop
        float e = als[n * 8 + head] + adv;
        e = (e > 0.f) ? e : 0.2f * e;
        float w = __expf(e);
        wsum += w;
        float2 hv = __half22float2(h1v[(size_t)n * 64 + lane]);
        accx += w * hv.x;
        accy += w * hv.y;
    }
    float inv = 1.f / (wsum + 1e-16f);
    float o0 = accx * inv + b1[lane * 2];
    float o1 = accy * inv + b1[lane * 2 + 1];
    o0 = (o0 > 0.f) ? o0 : (__expf(o0) - 1.f);  // ELU
    o1 = (o1 > 0.f) ? o1 : (__expf(o1) - 1.f);
    *(float2*)(act1 + (size_t)n * 128 + lane * 2) = make_float2(o0, o1);
}

// GEMM2: h2[N,64] = act1[N,128] @ W2[128,64] (fp16 out); epilogue computes
// scalar alpha2_s/alpha2_d per node via 8-lane shuffle reduction (fp32).
__global__ __launch_bounds__(256) void gemm2_kernel(const float* __restrict__ act1,
                                                    const float* __restrict__ W2,
                                                    const float* __restrict__ a2s,
                                                    const float* __restrict__ a2d,
                                                    __half* __restrict__ h2,
                                                    float* __restrict__ al2s,
                                                    float* __restrict__ al2d, int N) {
    __shared__ float Ws[128 * 64];
    __shared__ float Xs[32 * 128];
    int t = threadIdx.x;
    int row0 = blockIdx.x * 32;
    {
        const float4* wv = (const float4*)W2;
        float4* Wv = (float4*)Ws;
        for (int i = t; i < 2048; i += 256) Wv[i] = wv[i];
    }
    {
        const float4* xv = (const float4*)(act1 + (size_t)row0 * 128);
        float4* Xv = (float4*)Xs;
        int valid = (N - row0) * 32;
        for (int i = t; i < 1024; i += 256)
            Xv[i] = (i < valid) ? xv[i] : make_float4(0.f, 0.f, 0.f, 0.f);
    }
    __syncthreads();
    int r = t >> 3, g = t & 7;
    float acc[8];
#pragma unroll
    for (int j = 0; j < 8; j++) acc[j] = 0.f;
    const float* xr = Xs + r * 128;
#pragma unroll 4
    for (int k = 0; k < 128; k++) {
        float xv = xr[k];
        const float4* wr = (const float4*)(Ws + k * 64 + g * 8);
        float4 w0 = wr[0], w1 = wr[1];
        acc[0] += xv * w0.x; acc[1] += xv * w0.y;
        acc[2] += xv * w0.z; acc[3] += xv * w0.w;
        acc[4] += xv * w1.x; acc[5] += xv * w1.y;
        acc[6] += xv * w1.z; acc[7] += xv * w1.w;
    }
    float ps = 0.f, pd = 0.f;
#pragma unroll
    for (int j = 0; j < 8; j++) {
        ps += acc[j] * a2s[g * 8 + j];
        pd += acc[j] * a2d[g * 8 + j];
    }
#pragma unroll
    for (int off = 1; off < 8; off <<= 1) {
        ps += __shfl_xor(ps, off, 64);
        pd += __shfl_xor(pd, off, 64);
    }
    int n = row0 + r;
    if (n < N) {
        __align__(16) __half2 hv[4];
#pragma unroll
        for (int j = 0; j < 4; j++)
            hv[j] = __floats2half2_rn(acc[2 * j], acc[2 * j + 1]);
        *(float4*)(h2 + (size_t)n * 64 + g * 8) = *(float4*)&hv[0];
        if (g == 0) {
            al2s[n] = ps;
            al2d[n] = pd;
        }
    }
}

// Aggregation layer 2: wave per node, lane owns channel lane (C=64, 1 head).
// fp16 row gather, fp32 accumulate. Epilogue: +b2, store final output fp32.
__global__ __launch_bounds__(256) void agg2_kernel(const __half* __restrict__ h2,
                                                   const float* __restrict__ al2s,
                                                   const float* __restrict__ al2d,
                                                   const int* __restrict__ rowstart,
                                                   const int* __restrict__ esrc,
                                                   const float* __restrict__ b2,
                                                   float* __restrict__ out, int N) {
    int gtid = blockIdx.x * blockDim.x + threadIdx.x;
    int n = gtid >> 6;
    if (n >= N) return;
    int lane = threadIdx.x & 63;
    float adv = al2d[n];
    float acc = 0.f, wsum = 0.f;
    int beg = rowstart[n], end = rowstart[n + 1];
    for (int j = beg; j < end; j++) {
        int s = esrc[j];
        float e = al2s[s] + adv;
        e = (e > 0.f) ? e : 0.2f * e;
        float w = __expf(e);
        wsum += w;
        acc += w * __half2float(h2[(size_t)s * 64 + lane]);
    }
    {  // self loop
        float e = al2s[n] + adv;
        e = (e > 0.f) ? e : 0.2f * e;
        float w = __expf(e);
        wsum += w;
        acc += w * __half2float(h2[(size_t)n * 64 + lane]);
    }
    out[(size_t)n * 64 + lane] = acc / (wsum + 1e-16f) + b2[lane];
}

extern "C" void kernel_launch(void* const* d_in, const int* in_sizes, int n_in,
                              void* d_out, int out_size, void* d_ws, size_t ws_size,
                              hipStream_t stream) {
    (void)n_in; (void)out_size; (void)ws_size;
    const float* x   = (const float*)d_in[0];
    const int*   ei  = (const int*)d_in[1];
    const float* W1  = (const float*)d_in[2];
    const float* a1s = (const float*)d_in[3];
    const float* a1d = (const float*)d_in[4];
    const float* b1  = (const float*)d_in[5];
    const float* W2  = (const float*)d_in[6];
    const float* a2s = (const float*)d_in[7];
    const float* a2d = (const float*)d_in[8];
    const float* b2  = (const float*)d_in[9];
    float* out = (float*)d_out;

    const int N = in_sizes[0] / 128;
    const int E = in_sizes[1] / 2;
    const int* src = ei;
    const int* dst = ei + E;

    char* wp = (char*)d_ws;
    auto alloc = [&](size_t bytes) -> void* {
        void* p = (void*)wp;
        wp += (bytes + 255) & ~(size_t)255;
        return p;
    };
    __half* h1  = (__half*)alloc((size_t)N * 128 * 2);
    float* act1 = (float*)alloc((size_t)N * 128 * 4);
    __half* h2  = (__half*)alloc((size_t)N * 64 * 2);
    float* al1s = (float*)alloc((size_t)N * 8 * 4);
    float* al1d = (float*)alloc((size_t)N * 8 * 4);
    float* al2s = (float*)alloc((size_t)N * 4);
    float* al2d = (float*)alloc((size_t)N * 4);
    int* deg      = (int*)alloc((size_t)N * 4);
    int* rowstart = (int*)alloc((size_t)(N + 1) * 4);
    int* cursor   = (int*)alloc((size_t)N * 4);
    int* esrc     = (int*)alloc((size_t)E * 4);
    int* blocksum = (int*)alloc(256 * 4);

    const int nbScan = (N + 255) / 256;
    const int gridE  = (E + 255) / 256;
    const int gridN1 = (N + 31) / 32;
    const int gridAgg = (N * 64 + 255) / 256;

    hipMemsetAsync(deg, 0, (size_t)N * 4, stream);

    hist_kernel<<<gridE, 256, 0, stream>>>(dst, E, deg);
    scan1_kernel<<<nbScan, 256, 0, stream>>>(deg, N, rowstart, blocksum);
    scan2_kernel<<<1, 256, 0, stream>>>(blocksum, nbScan);
    scan3_kernel<<<(N + 256) / 256, 256, 0, stream>>>(rowstart, blocksum, cursor, N, E);
    scatter_kernel<<<gridE, 256, 0, stream>>>(src, dst, E, cursor, esrc);

    gemm1_kernel<<<gridN1, 256, 0, stream>>>(x, W1, a1s, a1d, h1, al1s, al1d, N);
    agg1_kernel<<<gridAgg, 256, 0, stream>>>(h1, al1s, al1d, rowstart, esrc, b1, act1, N);
    gemm2_kernel<<<gridN1, 256, 0, stream>>>(act1, W2, a2s, a2d, h2, al2s, al2d, N);
    agg2_kernel<<<gridAgg, 256, 0, stream>>>(h2, al2s, al2d, rowstart, esrc, b2, out, N);
}

// Round 3
// 310.202 us; speedup vs baseline: 1.4652x; 1.4163x over previous
//
#include <hip/hip_runtime.h>
#include <hip/hip_fp16.h>
#include <math.h>

// ---------------------------------------------------------------------------
// GAT 2-layer forward, N=50000, E=800000 (+N self loops), EMB=128,
// layer1: heads=8, C=16 (concat -> 128), layer2: heads=1, C=64.
// CSR-by-dst build per call, fused GEMM+alpha epilogues, one gather pass per
// layer, softmax without max-subtraction. h1/h2 in fp16 (gather traffic).
// R2: agg kernels use 4x16-lane edge groups per wave (4 gathers in flight,
//     ~4x MLP); gemms rewritten 4 rows x 4 cols/thread, bank-conflict-free.
// ---------------------------------------------------------------------------

__global__ __launch_bounds__(256) void hist_kernel(const int* __restrict__ dst, int E,
                                                   int* __restrict__ deg) {
    int i = blockIdx.x * 256 + threadIdx.x;
    if (i < E) atomicAdd(&deg[dst[i]], 1);
}

__global__ __launch_bounds__(256) void scan1_kernel(const int* __restrict__ deg, int N,
                                                    int* __restrict__ rowstart,
                                                    int* __restrict__ blocksum) {
    __shared__ int tmp[256];
    int t = threadIdx.x;
    int i = blockIdx.x * 256 + t;
    int v = (i < N) ? deg[i] : 0;
    tmp[t] = v;
    __syncthreads();
    for (int off = 1; off < 256; off <<= 1) {
        int x = (t >= off) ? tmp[t - off] : 0;
        __syncthreads();
        tmp[t] += x;
        __syncthreads();
    }
    if (i < N) rowstart[i] = tmp[t] - v;
    if (t == 255) blocksum[blockIdx.x] = tmp[t];
}

__global__ __launch_bounds__(256) void scan2_kernel(int* __restrict__ blocksum, int nb) {
    __shared__ int tmp[256];
    int t = threadIdx.x;
    int v = (t < nb) ? blocksum[t] : 0;
    tmp[t] = v;
    __syncthreads();
    for (int off = 1; off < 256; off <<= 1) {
        int x = (t >= off) ? tmp[t - off] : 0;
        __syncthreads();
        tmp[t] += x;
        __syncthreads();
    }
    if (t < nb) blocksum[t] = tmp[t] - v;
}

__global__ __launch_bounds__(256) void scan3_kernel(int* __restrict__ rowstart,
                                                    const int* __restrict__ blockoff,
                                                    int* __restrict__ cursor,
                                                    int N, int E) {
    int i = blockIdx.x * 256 + threadIdx.x;
    if (i < N) {
        int v = rowstart[i] + blockoff[i >> 8];
        rowstart[i] = v;
        cursor[i] = v;
    } else if (i == N) {
        rowstart[N] = E;
    }
}

__global__ __launch_bounds__(256) void scatter_kernel(const int* __restrict__ src,
                                                      const int* __restrict__ dst, int E,
                                                      int* __restrict__ cursor,
                                                      int* __restrict__ esrc) {
    int i = blockIdx.x * 256 + threadIdx.x;
    if (i < E) {
        int p = atomicAdd(&cursor[dst[i]], 1);
        esrc[p] = src[i];
    }
}

// GEMM1: h1[N,128] = x[N,128] @ W1[128,128] (fp16 out). 32-row tile, thread
// owns 4 rows x 4 cols. X read: broadcast + 2-way (free). W read: 32
// consecutive float4s (conflict-free). Epilogue: per-head alpha dots via
// 4-lane shuffle reduce.
__global__ __launch_bounds__(256) void gemm1_kernel(const float* __restrict__ x,
                                                    const float* __restrict__ W,
                                                    const float* __restrict__ a_s,
                                                    const float* __restrict__ a_d,
                                                    __half* __restrict__ h1,
                                                    float* __restrict__ als,
                                                    float* __restrict__ ald, int N) {
    __shared__ float Xs[32 * 128];  // 16 KB
    __shared__ float Ws[32 * 128];  // 16 KB
    int t = threadIdx.x;
    int row0 = blockIdx.x * 32;
    int cg = t & 31;   // cols cg*4 .. cg*4+3
    int rg = t >> 5;   // rows rg*4 .. rg*4+3
    {
        const float4* xv = (const float4*)(x + (size_t)row0 * 128);
        float4* Xv = (float4*)Xs;
        int valid = (N - row0) * 32;
        for (int i = t; i < 1024; i += 256)
            Xv[i] = (i < valid) ? xv[i] : make_float4(0.f, 0.f, 0.f, 0.f);
    }
    float acc[4][4];
#pragma unroll
    for (int i = 0; i < 4; i++)
#pragma unroll
        for (int j = 0; j < 4; j++) acc[i][j] = 0.f;

    for (int kt = 0; kt < 4; kt++) {
        __syncthreads();
        {
            const float4* wv = (const float4*)(W + (size_t)kt * 32 * 128);
            float4* Wv = (float4*)Ws;
            for (int i = t; i < 1024; i += 256) Wv[i] = wv[i];
        }
        __syncthreads();
        const float* xb = Xs + (size_t)rg * 4 * 128 + kt * 32;
#pragma unroll 8
        for (int kk = 0; kk < 32; kk++) {
            float4 w = *(const float4*)(Ws + kk * 128 + cg * 4);
            float x0 = xb[kk];
            float x1 = xb[128 + kk];
            float x2 = xb[256 + kk];
            float x3 = xb[384 + kk];
            acc[0][0] += x0 * w.x; acc[0][1] += x0 * w.y; acc[0][2] += x0 * w.z; acc[0][3] += x0 * w.w;
            acc[1][0] += x1 * w.x; acc[1][1] += x1 * w.y; acc[1][2] += x1 * w.z; acc[1][3] += x1 * w.w;
            acc[2][0] += x2 * w.x; acc[2][1] += x2 * w.y; acc[2][2] += x2 * w.z; acc[2][3] += x2 * w.w;
            acc[3][0] += x3 * w.x; acc[3][1] += x3 * w.y; acc[3][2] += x3 * w.z; acc[3][3] += x3 * w.w;
        }
    }
    int head = cg >> 2;
    int abase = head * 16 + (cg & 3) * 4;
    float as0 = a_s[abase], as1 = a_s[abase + 1], as2 = a_s[abase + 2], as3 = a_s[abase + 3];
    float ad0 = a_d[abase], ad1 = a_d[abase + 1], ad2 = a_d[abase + 2], ad3 = a_d[abase + 3];
#pragma unroll
    for (int i = 0; i < 4; i++) {
        int n = row0 + rg * 4 + i;
        if (n < N) {
            __align__(8) __half2 pk[2];
            pk[0] = __floats2half2_rn(acc[i][0], acc[i][1]);
            pk[1] = __floats2half2_rn(acc[i][2], acc[i][3]);
            *(float2*)(h1 + (size_t)n * 128 + cg * 4) = *(float2*)pk;
            float ds = acc[i][0] * as0 + acc[i][1] * as1 + acc[i][2] * as2 + acc[i][3] * as3;
            float dd = acc[i][0] * ad0 + acc[i][1] * ad1 + acc[i][2] * ad2 + acc[i][3] * ad3;
            ds += __shfl_xor(ds, 1, 64); ds += __shfl_xor(ds, 2, 64);
            dd += __shfl_xor(dd, 1, 64); dd += __shfl_xor(dd, 2, 64);
            if ((cg & 3) == 0) {
                als[n * 8 + head] = ds;
                ald[n * 8 + head] = dd;
            }
        }
    }
}

// Aggregation layer 1: one wave per dst node, split into 4 groups of 16
// lanes; group g processes edges beg+g, beg+g+4, ... (4 gathers in flight).
// Lane q in group owns channels 8q..8q+7 (16B fp16 load). Cross-group
// combine via shfl_xor(16,32); self-loop added post-reduction; grp 0 writes.
__global__ __launch_bounds__(256) void agg1_kernel(const __half* __restrict__ h1,
                                                   const float* __restrict__ als,
                                                   const float* __restrict__ ald,
                                                   const int* __restrict__ rowstart,
                                                   const int* __restrict__ esrc,
                                                   const float* __restrict__ b1,
                                                   float* __restrict__ act1, int N) {
    int gtid = blockIdx.x * 256 + threadIdx.x;
    int n = gtid >> 6;
    if (n >= N) return;
    int lane = threadIdx.x & 63;
    int grp = lane >> 4;
    int q = lane & 15;       // channels 8q..8q+7
    int head = q >> 1;
    const float4* h1v = (const float4*)h1;  // 16 float4 per row (128 halves)
    float adv = ald[n * 8 + head];
    float acc[8];
#pragma unroll
    for (int k = 0; k < 8; k++) acc[k] = 0.f;
    float wsum = 0.f;
    int beg = rowstart[n], end = rowstart[n + 1];
    for (int j = beg + grp; j < end; j += 4) {
        int s = esrc[j];
        float e = als[s * 8 + head] + adv;
        e = (e > 0.f) ? e : 0.2f * e;
        float w = __expf(e);
        wsum += w;
        float4 hv = h1v[(size_t)s * 16 + q];
        const __half2* hp = (const __half2*)&hv;
        float2 f0 = __half22float2(hp[0]);
        float2 f1 = __half22float2(hp[1]);
        float2 f2 = __half22float2(hp[2]);
        float2 f3 = __half22float2(hp[3]);
        acc[0] += w * f0.x; acc[1] += w * f0.y;
        acc[2] += w * f1.x; acc[3] += w * f1.y;
        acc[4] += w * f2.x; acc[5] += w * f2.y;
        acc[6] += w * f3.x; acc[7] += w * f3.y;
    }
#pragma unroll
    for (int off = 16; off < 64; off <<= 1) {
        wsum += __shfl_xor(wsum, off, 64);
#pragma unroll
        for (int k = 0; k < 8; k++) acc[k] += __shfl_xor(acc[k], off, 64);
    }
    {  // self loop (identical on all lanes)
        float e = als[n * 8 + head] + adv;
        e = (e > 0.f) ? e : 0.2f * e;
        float w = __expf(e);
        wsum += w;
        float4 hv = h1v[(size_t)n * 16 + q];
        const __half2* hp = (const __half2*)&hv;
        float2 f0 = __half22float2(hp[0]);
        float2 f1 = __half22float2(hp[1]);
        float2 f2 = __half22float2(hp[2]);
        float2 f3 = __half22float2(hp[3]);
        acc[0] += w * f0.x; acc[1] += w * f0.y;
        acc[2] += w * f1.x; acc[3] += w * f1.y;
        acc[4] += w * f2.x; acc[5] += w * f2.y;
        acc[6] += w * f3.x; acc[7] += w * f3.y;
    }
    if (grp == 0) {
        float inv = 1.f / (wsum + 1e-16f);
        float o[8];
#pragma unroll
        for (int k = 0; k < 8; k++) {
            o[k] = acc[k] * inv + b1[q * 8 + k];
            o[k] = (o[k] > 0.f) ? o[k] : (__expf(o[k]) - 1.f);  // ELU
        }
        float4* ov = (float4*)(act1 + (size_t)n * 128 + q * 8);
        ov[0] = make_float4(o[0], o[1], o[2], o[3]);
        ov[1] = make_float4(o[4], o[5], o[6], o[7]);
    }
}

// GEMM2: h2[N,64] = act1[N,128] @ W2[128,64] (fp16 out). 64-row tile, thread
// owns 4 rows x 4 cols; whole W2 in LDS. Epilogue: scalar alpha dots via
// 16-lane shuffle reduce.
__global__ __launch_bounds__(256) void gemm2_kernel(const float* __restrict__ act1,
                                                    const float* __restrict__ W2,
                                                    const float* __restrict__ a2s,
                                                    const float* __restrict__ a2d,
                                                    __half* __restrict__ h2,
                                                    float* __restrict__ al2s,
                                                    float* __restrict__ al2d, int N) {
    __shared__ float Ws[128 * 64];  // 32 KB
    __shared__ float Xs[64 * 128];  // 32 KB
    int t = threadIdx.x;
    int row0 = blockIdx.x * 64;
    int cg = t & 15;   // cols cg*4
    int rg = t >> 4;   // rows rg*4
    {
        const float4* wv = (const float4*)W2;
        float4* Wv = (float4*)Ws;
        for (int i = t; i < 2048; i += 256) Wv[i] = wv[i];
    }
    {
        const float4* xv = (const float4*)(act1 + (size_t)row0 * 128);
        float4* Xv = (float4*)Xs;
        int valid = (N - row0) * 32;
        for (int i = t; i < 2048; i += 256)
            Xv[i] = (i < valid) ? xv[i] : make_float4(0.f, 0.f, 0.f, 0.f);
    }
    __syncthreads();
    float acc[4][4];
#pragma unroll
    for (int i = 0; i < 4; i++)
#pragma unroll
        for (int j = 0; j < 4; j++) acc[i][j] = 0.f;
    const float* xb = Xs + (size_t)rg * 4 * 128;
#pragma unroll 8
    for (int k = 0; k < 128; k++) {
        float4 w = *(const float4*)(Ws + k * 64 + cg * 4);
        float x0 = xb[k];
        float x1 = xb[128 + k];
        float x2 = xb[256 + k];
        float x3 = xb[384 + k];
        acc[0][0] += x0 * w.x; acc[0][1] += x0 * w.y; acc[0][2] += x0 * w.z; acc[0][3] += x0 * w.w;
        acc[1][0] += x1 * w.x; acc[1][1] += x1 * w.y; acc[1][2] += x1 * w.z; acc[1][3] += x1 * w.w;
        acc[2][0] += x2 * w.x; acc[2][1] += x2 * w.y; acc[2][2] += x2 * w.z; acc[2][3] += x2 * w.w;
        acc[3][0] += x3 * w.x; acc[3][1] += x3 * w.y; acc[3][2] += x3 * w.z; acc[3][3] += x3 * w.w;
    }
    float as0 = a2s[cg * 4], as1 = a2s[cg * 4 + 1], as2 = a2s[cg * 4 + 2], as3 = a2s[cg * 4 + 3];
    float ad0 = a2d[cg * 4], ad1 = a2d[cg * 4 + 1], ad2 = a2d[cg * 4 + 2], ad3 = a2d[cg * 4 + 3];
#pragma unroll
    for (int i = 0; i < 4; i++) {
        int n = row0 + rg * 4 + i;
        if (n < N) {
            __align__(8) __half2 pk[2];
            pk[0] = __floats2half2_rn(acc[i][0], acc[i][1]);
            pk[1] = __floats2half2_rn(acc[i][2], acc[i][3]);
            *(float2*)(h2 + (size_t)n * 64 + cg * 4) = *(float2*)pk;
            float ps = acc[i][0] * as0 + acc[i][1] * as1 + acc[i][2] * as2 + acc[i][3] * as3;
            float pd = acc[i][0] * ad0 + acc[i][1] * ad1 + acc[i][2] * ad2 + acc[i][3] * ad3;
#pragma unroll
            for (int off = 1; off < 16; off <<= 1) {
                ps += __shfl_xor(ps, off, 64);
                pd += __shfl_xor(pd, off, 64);
            }
            if (cg == 0) {
                al2s[n] = ps;
                al2d[n] = pd;
            }
        }
    }
}

// Aggregation layer 2: wave per node, 4 groups of 16 lanes; lane q owns
// channels 4q..4q+3 (8B fp16 load). Epilogue: +b2, fp32 out.
__global__ __launch_bounds__(256) void agg2_kernel(const __half* __restrict__ h2,
                                                   const float* __restrict__ al2s,
                                                   const float* __restrict__ al2d,
                                                   const int* __restrict__ rowstart,
                                                   const int* __restrict__ esrc,
                                                   const float* __restrict__ b2,
                                                   float* __restrict__ out, int N) {
    int gtid = blockIdx.x * 256 + threadIdx.x;
    int n = gtid >> 6;
    if (n >= N) return;
    int lane = threadIdx.x & 63;
    int grp = lane >> 4;
    int q = lane & 15;  // channels 4q..4q+3
    const float2* h2v = (const float2*)h2;  // 16 float2 per row (64 halves)
    float adv = al2d[n];
    float acc[4];
#pragma unroll
    for (int k = 0; k < 4; k++) acc[k] = 0.f;
    float wsum = 0.f;
    int beg = rowstart[n], end = rowstart[n + 1];
    for (int j = beg + grp; j < end; j += 4) {
        int s = esrc[j];
        float e = al2s[s] + adv;
        e = (e > 0.f) ? e : 0.2f * e;
        float w = __expf(e);
        wsum += w;
        float2 hv = h2v[(size_t)s * 16 + q];
        const __half2* hp = (const __half2*)&hv;
        float2 f0 = __half22float2(hp[0]);
        float2 f1 = __half22float2(hp[1]);
        acc[0] += w * f0.x; acc[1] += w * f0.y;
        acc[2] += w * f1.x; acc[3] += w * f1.y;
    }
#pragma unroll
    for (int off = 16; off < 64; off <<= 1) {
        wsum += __shfl_xor(wsum, off, 64);
#pragma unroll
        for (int k = 0; k < 4; k++) acc[k] += __shfl_xor(acc[k], off, 64);
    }
    {  // self loop
        float e = al2s[n] + adv;
        e = (e > 0.f) ? e : 0.2f * e;
        float w = __expf(e);
        wsum += w;
        float2 hv = h2v[(size_t)n * 16 + q];
        const __half2* hp = (const __half2*)&hv;
        float2 f0 = __half22float2(hp[0]);
        float2 f1 = __half22float2(hp[1]);
        acc[0] += w * f0.x; acc[1] += w * f0.y;
        acc[2] += w * f1.x; acc[3] += w * f1.y;
    }
    if (grp == 0) {
        float inv = 1.f / (wsum + 1e-16f);
        *(float4*)(out + (size_t)n * 64 + q * 4) =
            make_float4(acc[0] * inv + b2[q * 4],
                        acc[1] * inv + b2[q * 4 + 1],
                        acc[2] * inv + b2[q * 4 + 2],
                        acc[3] * inv + b2[q * 4 + 3]);
    }
}

extern "C" void kernel_launch(void* const* d_in, const int* in_sizes, int n_in,
                              void* d_out, int out_size, void* d_ws, size_t ws_size,
                              hipStream_t stream) {
    (void)n_in; (void)out_size; (void)ws_size;
    const float* x   = (const float*)d_in[0];
    const int*   ei  = (const int*)d_in[1];
    const float* W1  = (const float*)d_in[2];
    const float* a1s = (const float*)d_in[3];
    const float* a1d = (const float*)d_in[4];
    const float* b1  = (const float*)d_in[5];
    const float* W2  = (const float*)d_in[6];
    const float* a2s = (const float*)d_in[7];
    const float* a2d = (const float*)d_in[8];
    const float* b2  = (const float*)d_in[9];
    float* out = (float*)d_out;

    const int N = in_sizes[0] / 128;
    const int E = in_sizes[1] / 2;
    const int* src = ei;
    const int* dst = ei + E;

    char* wp = (char*)d_ws;
    auto alloc = [&](size_t bytes) -> void* {
        void* p = (void*)wp;
        wp += (bytes + 255) & ~(size_t)255;
        return p;
    };
    __half* h1  = (__half*)alloc((size_t)N * 128 * 2);
    float* act1 = (float*)alloc((size_t)N * 128 * 4);
    __half* h2  = (__half*)alloc((size_t)N * 64 * 2);
    float* al1s = (float*)alloc((size_t)N * 8 * 4);
    float* al1d = (float*)alloc((size_t)N * 8 * 4);
    float* al2s = (float*)alloc((size_t)N * 4);
    float* al2d = (float*)alloc((size_t)N * 4);
    int* deg      = (int*)alloc((size_t)N * 4);
    int* rowstart = (int*)alloc((size_t)(N + 1) * 4);
    int* cursor   = (int*)alloc((size_t)N * 4);
    int* esrc     = (int*)alloc((size_t)E * 4);
    int* blocksum = (int*)alloc(256 * 4);

    const int nbScan = (N + 255) / 256;
    const int gridE  = (E + 255) / 256;
    const int gridG1 = (N + 31) / 32;
    const int gridG2 = (N + 63) / 64;
    const int gridAgg = (N * 64 + 255) / 256;

    hipMemsetAsync(deg, 0, (size_t)N * 4, stream);

    hist_kernel<<<gridE, 256, 0, stream>>>(dst, E, deg);
    scan1_kernel<<<nbScan, 256, 0, stream>>>(deg, N, rowstart, blocksum);
    scan2_kernel<<<1, 256, 0, stream>>>(blocksum, nbScan);
    scan3_kernel<<<(N + 256) / 256, 256, 0, stream>>>(rowstart, blocksum, cursor, N, E);
    scatter_kernel<<<gridE, 256, 0, stream>>>(src, dst, E, cursor, esrc);

    gemm1_kernel<<<gridG1, 256, 0, stream>>>(x, W1, a1s, a1d, h1, al1s, al1d, N);
    agg1_kernel<<<gridAgg, 256, 0, stream>>>(h1, al1s, al1d, rowstart, esrc, b1, act1, N);
    gemm2_kernel<<<gridG2, 256, 0, stream>>>(act1, W2, a2s, a2d, h2, al2s, al2d, N);
    agg2_kernel<<<gridAgg, 256, 0, stream>>>(h2, al2s, al2d, rowstart, esrc, b2, out, N);
}

// Round 4
// 289.445 us; speedup vs baseline: 1.5703x; 1.0717x over previous
//
#include <hip/hip_runtime.h>
#include <hip/hip_fp16.h>
#include <math.h>

// ---------------------------------------------------------------------------
// GAT 2-layer forward, N=50000, E=800000 (+N self loops), EMB=128,
// layer1: heads=8, C=16 (concat -> 128), layer2: heads=1, C=64.
// CSR-by-dst build per call, fused GEMM+alpha epilogues, one gather pass per
// layer, softmax without max-subtraction. h1/h2 in fp16.
// R3: scatter partitioned into 8 dst-ranges committed by blockIdx&7 (XCD
//     round-robin) -> esrc write lines stay in ONE XCD's L2 (kills the
//     64B/edge write-allocate bounce). agg kernels: 8x8-lane groups
//     (8 gathers in flight per wave).
// ---------------------------------------------------------------------------

__global__ __launch_bounds__(256) void hist_kernel(const int* __restrict__ dst, int E,
                                                   int* __restrict__ deg) {
    int i = blockIdx.x * 256 + threadIdx.x;
    if (i < E) atomicAdd(&deg[dst[i]], 1);
}

__global__ __launch_bounds__(256) void scan1_kernel(const int* __restrict__ deg, int N,
                                                    int* __restrict__ rowstart,
                                                    int* __restrict__ blocksum) {
    __shared__ int tmp[256];
    int t = threadIdx.x;
    int i = blockIdx.x * 256 + t;
    int v = (i < N) ? deg[i] : 0;
    tmp[t] = v;
    __syncthreads();
    for (int off = 1; off < 256; off <<= 1) {
        int x = (t >= off) ? tmp[t - off] : 0;
        __syncthreads();
        tmp[t] += x;
        __syncthreads();
    }
    if (i < N) rowstart[i] = tmp[t] - v;
    if (t == 255) blocksum[blockIdx.x] = tmp[t];
}

__global__ __launch_bounds__(256) void scan2_kernel(int* __restrict__ blocksum, int nb) {
    __shared__ int tmp[256];
    int t = threadIdx.x;
    int v = (t < nb) ? blocksum[t] : 0;
    tmp[t] = v;
    __syncthreads();
    for (int off = 1; off < 256; off <<= 1) {
        int x = (t >= off) ? tmp[t - off] : 0;
        __syncthreads();
        tmp[t] += x;
        __syncthreads();
    }
    if (t < nb) blocksum[t] = tmp[t] - v;
}

__global__ __launch_bounds__(256) void scan3_kernel(int* __restrict__ rowstart,
                                                    const int* __restrict__ blockoff,
                                                    int* __restrict__ cursor,
                                                    int N, int E) {
    int i = blockIdx.x * 256 + threadIdx.x;
    if (i < N) {
        int v = rowstart[i] + blockoff[i >> 8];
        rowstart[i] = v;
        cursor[i] = v;
    } else if (i == N) {
        rowstart[N] = E;
    }
}

// Bucketed scatter: block (blockIdx&7) commits only dst in its 1/8 range of
// nodes -> its esrc writes land in an ~E/8*4B region owned by one XCD's L2.
// Each 1024-edge chunk is streamed by 8 blocks (redundant reads, MALL-hit).
__global__ __launch_bounds__(256) void scatter_kernel(const int* __restrict__ src,
                                                      const int* __restrict__ dst,
                                                      int E, int N,
                                                      int* __restrict__ cursor,
                                                      int* __restrict__ esrc) {
    int b = blockIdx.x & 7;
    int chunk = blockIdx.x >> 3;
    int bdiv = (N + 7) >> 3;
    int blo = b * bdiv;
    int bhi = blo + bdiv;
    int base = chunk * 1024 + threadIdx.x;
#pragma unroll
    for (int u = 0; u < 4; u++) {
        int i = base + u * 256;
        if (i < E) {
            int d = dst[i];
            int s = src[i];
            if (d >= blo && d < bhi) {
                int p = atomicAdd(&cursor[d], 1);
                esrc[p] = s;
            }
        }
    }
}

// GEMM1: h1[N,128] = x[N,128] @ W1[128,128] (fp16 out). 32-row tile, thread
// owns 4 rows x 4 cols. Epilogue: per-head alpha dots via 4-lane shuffle.
__global__ __launch_bounds__(256) void gemm1_kernel(const float* __restrict__ x,
                                                    const float* __restrict__ W,
                                                    const float* __restrict__ a_s,
                                                    const float* __restrict__ a_d,
                                                    __half* __restrict__ h1,
                                                    float* __restrict__ als,
                                                    float* __restrict__ ald, int N) {
    __shared__ float Xs[32 * 128];
    __shared__ float Ws[32 * 128];
    int t = threadIdx.x;
    int row0 = blockIdx.x * 32;
    int cg = t & 31;
    int rg = t >> 5;
    {
        const float4* xv = (const float4*)(x + (size_t)row0 * 128);
        float4* Xv = (float4*)Xs;
        int valid = (N - row0) * 32;
        for (int i = t; i < 1024; i += 256)
            Xv[i] = (i < valid) ? xv[i] : make_float4(0.f, 0.f, 0.f, 0.f);
    }
    float acc[4][4];
#pragma unroll
    for (int i = 0; i < 4; i++)
#pragma unroll
        for (int j = 0; j < 4; j++) acc[i][j] = 0.f;

    for (int kt = 0; kt < 4; kt++) {
        __syncthreads();
        {
            const float4* wv = (const float4*)(W + (size_t)kt * 32 * 128);
            float4* Wv = (float4*)Ws;
            for (int i = t; i < 1024; i += 256) Wv[i] = wv[i];
        }
        __syncthreads();
        const float* xb = Xs + (size_t)rg * 4 * 128 + kt * 32;
#pragma unroll 8
        for (int kk = 0; kk < 32; kk++) {
            float4 w = *(const float4*)(Ws + kk * 128 + cg * 4);
            float x0 = xb[kk];
            float x1 = xb[128 + kk];
            float x2 = xb[256 + kk];
            float x3 = xb[384 + kk];
            acc[0][0] += x0 * w.x; acc[0][1] += x0 * w.y; acc[0][2] += x0 * w.z; acc[0][3] += x0 * w.w;
            acc[1][0] += x1 * w.x; acc[1][1] += x1 * w.y; acc[1][2] += x1 * w.z; acc[1][3] += x1 * w.w;
            acc[2][0] += x2 * w.x; acc[2][1] += x2 * w.y; acc[2][2] += x2 * w.z; acc[2][3] += x2 * w.w;
            acc[3][0] += x3 * w.x; acc[3][1] += x3 * w.y; acc[3][2] += x3 * w.z; acc[3][3] += x3 * w.w;
        }
    }
    int head = cg >> 2;
    int abase = head * 16 + (cg & 3) * 4;
    float as0 = a_s[abase], as1 = a_s[abase + 1], as2 = a_s[abase + 2], as3 = a_s[abase + 3];
    float ad0 = a_d[abase], ad1 = a_d[abase + 1], ad2 = a_d[abase + 2], ad3 = a_d[abase + 3];
#pragma unroll
    for (int i = 0; i < 4; i++) {
        int n = row0 + rg * 4 + i;
        if (n < N) {
            __align__(8) __half2 pk[2];
            pk[0] = __floats2half2_rn(acc[i][0], acc[i][1]);
            pk[1] = __floats2half2_rn(acc[i][2], acc[i][3]);
            *(float2*)(h1 + (size_t)n * 128 + cg * 4) = *(float2*)pk;
            float ds = acc[i][0] * as0 + acc[i][1] * as1 + acc[i][2] * as2 + acc[i][3] * as3;
            float dd = acc[i][0] * ad0 + acc[i][1] * ad1 + acc[i][2] * ad2 + acc[i][3] * ad3;
            ds += __shfl_xor(ds, 1, 64); ds += __shfl_xor(ds, 2, 64);
            dd += __shfl_xor(dd, 1, 64); dd += __shfl_xor(dd, 2, 64);
            if ((cg & 3) == 0) {
                als[n * 8 + head] = ds;
                ald[n * 8 + head] = dd;
            }
        }
    }
}

// Aggregation layer 1: one wave per dst node, 8 groups of 8 lanes; group g
// processes edges beg+g, beg+g+8, ... (8 gathers in flight). Lane q (=lane&7)
// owns head q's 16 channels (2 x float4 fp16). Cross-group combine via
// shfl_xor(8,16,32); self-loop added post-reduction; lanes 0..7 write.
__global__ __launch_bounds__(256) void agg1_kernel(const __half* __restrict__ h1,
                                                   const float* __restrict__ als,
                                                   const float* __restrict__ ald,
                                                   const int* __restrict__ rowstart,
                                                   const int* __restrict__ esrc,
                                                   const float* __restrict__ b1,
                                                   float* __restrict__ act1, int N) {
    int gtid = blockIdx.x * 256 + threadIdx.x;
    int n = gtid >> 6;
    if (n >= N) return;
    int lane = threadIdx.x & 63;
    int grp = lane >> 3;
    int q = lane & 7;        // head q, channels 16q..16q+15
    const float4* h1v = (const float4*)h1;  // 16 float4 per row
    float adv = ald[n * 8 + q];
    float acc[16];
#pragma unroll
    for (int k = 0; k < 16; k++) acc[k] = 0.f;
    float wsum = 0.f;
    int beg = rowstart[n], end = rowstart[n + 1];
    for (int j = beg + grp; j < end; j += 8) {
        int s = esrc[j];
        float e = als[s * 8 + q] + adv;
        e = (e > 0.f) ? e : 0.2f * e;
        float w = __expf(e);
        wsum += w;
        float4 hv0 = h1v[(size_t)s * 16 + 2 * q];
        float4 hv1 = h1v[(size_t)s * 16 + 2 * q + 1];
        const __half2* p0 = (const __half2*)&hv0;
        const __half2* p1 = (const __half2*)&hv1;
#pragma unroll
        for (int k = 0; k < 4; k++) {
            float2 f = __half22float2(p0[k]);
            acc[2 * k] += w * f.x;
            acc[2 * k + 1] += w * f.y;
        }
#pragma unroll
        for (int k = 0; k < 4; k++) {
            float2 f = __half22float2(p1[k]);
            acc[8 + 2 * k] += w * f.x;
            acc[8 + 2 * k + 1] += w * f.y;
        }
    }
#pragma unroll
    for (int off = 8; off < 64; off <<= 1) {
        wsum += __shfl_xor(wsum, off, 64);
#pragma unroll
        for (int k = 0; k < 16; k++) acc[k] += __shfl_xor(acc[k], off, 64);
    }
    {  // self loop (computed on all lanes; each lane's q-channels)
        float e = als[n * 8 + q] + adv;
        e = (e > 0.f) ? e : 0.2f * e;
        float w = __expf(e);
        wsum += w;
        float4 hv0 = h1v[(size_t)n * 16 + 2 * q];
        float4 hv1 = h1v[(size_t)n * 16 + 2 * q + 1];
        const __half2* p0 = (const __half2*)&hv0;
        const __half2* p1 = (const __half2*)&hv1;
#pragma unroll
        for (int k = 0; k < 4; k++) {
            float2 f = __half22float2(p0[k]);
            acc[2 * k] += w * f.x;
            acc[2 * k + 1] += w * f.y;
        }
#pragma unroll
        for (int k = 0; k < 4; k++) {
            float2 f = __half22float2(p1[k]);
            acc[8 + 2 * k] += w * f.x;
            acc[8 + 2 * k + 1] += w * f.y;
        }
    }
    if (grp == 0) {
        float inv = 1.f / (wsum + 1e-16f);
        float o[16];
#pragma unroll
        for (int k = 0; k < 16; k++) {
            o[k] = acc[k] * inv + b1[q * 16 + k];
            o[k] = (o[k] > 0.f) ? o[k] : (__expf(o[k]) - 1.f);  // ELU
        }
        float4* ov = (float4*)(act1 + (size_t)n * 128 + q * 16);
        ov[0] = make_float4(o[0], o[1], o[2], o[3]);
        ov[1] = make_float4(o[4], o[5], o[6], o[7]);
        ov[2] = make_float4(o[8], o[9], o[10], o[11]);
        ov[3] = make_float4(o[12], o[13], o[14], o[15]);
    }
}

// GEMM2: h2[N,64] = act1[N,128] @ W2[128,64] (fp16 out). 64-row tile, thread
// owns 4 rows x 4 cols; whole W2 in LDS.
__global__ __launch_bounds__(256) void gemm2_kernel(const float* __restrict__ act1,
                                                    const float* __restrict__ W2,
                                                    const float* __restrict__ a2s,
                                                    const float* __restrict__ a2d,
                                                    __half* __restrict__ h2,
                                                    float* __restrict__ al2s,
                                                    float* __restrict__ al2d, int N) {
    __shared__ float Ws[128 * 64];
    __shared__ float Xs[64 * 128];
    int t = threadIdx.x;
    int row0 = blockIdx.x * 64;
    int cg = t & 15;
    int rg = t >> 4;
    {
        const float4* wv = (const float4*)W2;
        float4* Wv = (float4*)Ws;
        for (int i = t; i < 2048; i += 256) Wv[i] = wv[i];
    }
    {
        const float4* xv = (const float4*)(act1 + (size_t)row0 * 128);
        float4* Xv = (float4*)Xs;
        int valid = (N - row0) * 32;
        for (int i = t; i < 2048; i += 256)
            Xv[i] = (i < valid) ? xv[i] : make_float4(0.f, 0.f, 0.f, 0.f);
    }
    __syncthreads();
    float acc[4][4];
#pragma unroll
    for (int i = 0; i < 4; i++)
#pragma unroll
        for (int j = 0; j < 4; j++) acc[i][j] = 0.f;
    const float* xb = Xs + (size_t)rg * 4 * 128;
#pragma unroll 8
    for (int k = 0; k < 128; k++) {
        float4 w = *(const float4*)(Ws + k * 64 + cg * 4);
        float x0 = xb[k];
        float x1 = xb[128 + k];
        float x2 = xb[256 + k];
        float x3 = xb[384 + k];
        acc[0][0] += x0 * w.x; acc[0][1] += x0 * w.y; acc[0][2] += x0 * w.z; acc[0][3] += x0 * w.w;
        acc[1][0] += x1 * w.x; acc[1][1] += x1 * w.y; acc[1][2] += x1 * w.z; acc[1][3] += x1 * w.w;
        acc[2][0] += x2 * w.x; acc[2][1] += x2 * w.y; acc[2][2] += x2 * w.z; acc[2][3] += x2 * w.w;
        acc[3][0] += x3 * w.x; acc[3][1] += x3 * w.y; acc[3][2] += x3 * w.z; acc[3][3] += x3 * w.w;
    }
    float as0 = a2s[cg * 4], as1 = a2s[cg * 4 + 1], as2 = a2s[cg * 4 + 2], as3 = a2s[cg * 4 + 3];
    float ad0 = a2d[cg * 4], ad1 = a2d[cg * 4 + 1], ad2 = a2d[cg * 4 + 2], ad3 = a2d[cg * 4 + 3];
#pragma unroll
    for (int i = 0; i < 4; i++) {
        int n = row0 + rg * 4 + i;
        if (n < N) {
            __align__(8) __half2 pk[2];
            pk[0] = __floats2half2_rn(acc[i][0], acc[i][1]);
            pk[1] = __floats2half2_rn(acc[i][2], acc[i][3]);
            *(float2*)(h2 + (size_t)n * 64 + cg * 4) = *(float2*)pk;
            float ps = acc[i][0] * as0 + acc[i][1] * as1 + acc[i][2] * as2 + acc[i][3] * as3;
            float pd = acc[i][0] * ad0 + acc[i][1] * ad1 + acc[i][2] * ad2 + acc[i][3] * ad3;
#pragma unroll
            for (int off = 1; off < 16; off <<= 1) {
                ps += __shfl_xor(ps, off, 64);
                pd += __shfl_xor(pd, off, 64);
            }
            if (cg == 0) {
                al2s[n] = ps;
                al2d[n] = pd;
            }
        }
    }
}

// Aggregation layer 2: wave per node, 8 groups of 8 lanes; lane q owns
// channels 8q..8q+7 (1 x float4 fp16). Epilogue: +b2, fp32 out.
__global__ __launch_bounds__(256) void agg2_kernel(const __half* __restrict__ h2,
                                                   const float* __restrict__ al2s,
                                                   const float* __restrict__ al2d,
                                                   const int* __restrict__ rowstart,
                                                   const int* __restrict__ esrc,
                                                   const float* __restrict__ b2,
                                                   float* __restrict__ out, int N) {
    int gtid = blockIdx.x * 256 + threadIdx.x;
    int n = gtid >> 6;
    if (n >= N) return;
    int lane = threadIdx.x & 63;
    int grp = lane >> 3;
    int q = lane & 7;  // channels 8q..8q+7
    const float4* h2v = (const float4*)h2;  // 8 float4 per row
    float adv = al2d[n];
    float acc[8];
#pragma unroll
    for (int k = 0; k < 8; k++) acc[k] = 0.f;
    float wsum = 0.f;
    int beg = rowstart[n], end = rowstart[n + 1];
    for (int j = beg + grp; j < end; j += 8) {
        int s = esrc[j];
        float e = al2s[s] + adv;
        e = (e > 0.f) ? e : 0.2f * e;
        float w = __expf(e);
        wsum += w;
        float4 hv = h2v[(size_t)s * 8 + q];
        const __half2* hp = (const __half2*)&hv;
#pragma unroll
        for (int k = 0; k < 4; k++) {
            float2 f = __half22float2(hp[k]);
            acc[2 * k] += w * f.x;
            acc[2 * k + 1] += w * f.y;
        }
    }
#pragma unroll
    for (int off = 8; off < 64; off <<= 1) {
        wsum += __shfl_xor(wsum, off, 64);
#pragma unroll
        for (int k = 0; k < 8; k++) acc[k] += __shfl_xor(acc[k], off, 64);
    }
    {  // self loop
        float e = al2s[n] + adv;
        e = (e > 0.f) ? e : 0.2f * e;
        float w = __expf(e);
        wsum += w;
        float4 hv = h2v[(size_t)n * 8 + q];
        const __half2* hp = (const __half2*)&hv;
#pragma unroll
        for (int k = 0; k < 4; k++) {
            float2 f = __half22float2(hp[k]);
            acc[2 * k] += w * f.x;
            acc[2 * k + 1] += w * f.y;
        }
    }
    if (grp == 0) {
        float inv = 1.f / (wsum + 1e-16f);
        float4* ov = (float4*)(out + (size_t)n * 64 + q * 8);
        ov[0] = make_float4(acc[0] * inv + b2[q * 8],
                            acc[1] * inv + b2[q * 8 + 1],
                            acc[2] * inv + b2[q * 8 + 2],
                            acc[3] * inv + b2[q * 8 + 3]);
        ov[1] = make_float4(acc[4] * inv + b2[q * 8 + 4],
                            acc[5] * inv + b2[q * 8 + 5],
                            acc[6] * inv + b2[q * 8 + 6],
                            acc[7] * inv + b2[q * 8 + 7]);
    }
}

extern "C" void kernel_launch(void* const* d_in, const int* in_sizes, int n_in,
                              void* d_out, int out_size, void* d_ws, size_t ws_size,
                              hipStream_t stream) {
    (void)n_in; (void)out_size; (void)ws_size;
    const float* x   = (const float*)d_in[0];
    const int*   ei  = (const int*)d_in[1];
    const float* W1  = (const float*)d_in[2];
    const float* a1s = (const float*)d_in[3];
    const float* a1d = (const float*)d_in[4];
    const float* b1  = (const float*)d_in[5];
    const float* W2  = (const float*)d_in[6];
    const float* a2s = (const float*)d_in[7];
    const float* a2d = (const float*)d_in[8];
    const float* b2  = (const float*)d_in[9];
    float* out = (float*)d_out;

    const int N = in_sizes[0] / 128;
    const int E = in_sizes[1] / 2;
    const int* src = ei;
    const int* dst = ei + E;

    char* wp = (char*)d_ws;
    auto alloc = [&](size_t bytes) -> void* {
        void* p = (void*)wp;
        wp += (bytes + 255) & ~(size_t)255;
        return p;
    };
    __half* h1  = (__half*)alloc((size_t)N * 128 * 2);
    float* act1 = (float*)alloc((size_t)N * 128 * 4);
    __half* h2  = (__half*)alloc((size_t)N * 64 * 2);
    float* al1s = (float*)alloc((size_t)N * 8 * 4);
    float* al1d = (float*)alloc((size_t)N * 8 * 4);
    float* al2s = (float*)alloc((size_t)N * 4);
    float* al2d = (float*)alloc((size_t)N * 4);
    int* deg      = (int*)alloc((size_t)N * 4);
    int* rowstart = (int*)alloc((size_t)(N + 1) * 4);
    int* cursor   = (int*)alloc((size_t)N * 4);
    int* esrc     = (int*)alloc((size_t)E * 4);
    int* blocksum = (int*)alloc(256 * 4);

    const int nbScan = (N + 255) / 256;
    const int gridE  = (E + 255) / 256;
    const int gridScat = ((E + 1023) / 1024) * 8;
    const int gridG1 = (N + 31) / 32;
    const int gridG2 = (N + 63) / 64;
    const int gridAgg = (N * 64 + 255) / 256;

    hipMemsetAsync(deg, 0, (size_t)N * 4, stream);

    hist_kernel<<<gridE, 256, 0, stream>>>(dst, E, deg);
    scan1_kernel<<<nbScan, 256, 0, stream>>>(deg, N, rowstart, blocksum);
    scan2_kernel<<<1, 256, 0, stream>>>(blocksum, nbScan);
    scan3_kernel<<<(N + 256) / 256, 256, 0, stream>>>(rowstart, blocksum, cursor, N, E);
    scatter_kernel<<<gridScat, 256, 0, stream>>>(src, dst, E, N, cursor, esrc);

    gemm1_kernel<<<gridG1, 256, 0, stream>>>(x, W1, a1s, a1d, h1, al1s, al1d, N);
    agg1_kernel<<<gridAgg, 256, 0, stream>>>(h1, al1s, al1d, rowstart, esrc, b1, act1, N);
    gemm2_kernel<<<gridG2, 256, 0, stream>>>(act1, W2, a2s, a2d, h2, al2s, al2d, N);
    agg2_kernel<<<gridAgg, 256, 0, stream>>>(h2, al2s, al2d, rowstart, esrc, b2, out, N);
}

// Round 5
// 287.068 us; speedup vs baseline: 1.5833x; 1.0083x over previous
//
#include <hip/hip_runtime.h>
#include <hip/hip_fp16.h>
#include <math.h>

// ---------------------------------------------------------------------------
// GAT 2-layer forward, N=50000, E=800000 (+N self loops), EMB=128,
// layer1: heads=8, C=16 (concat -> 128), layer2: heads=1, C=64.
// CSR-by-dst build per call, fused GEMM+alpha epilogues, one gather pass per
// layer, softmax without max-subtraction. h1/h2/act1 in fp16.
// R4 post-mortem: agg1 co-bound VALU(59%)+fetch(39%). R5: packed __hfma2
// accumulation in agg loops (~2x less VALU), act1 fp16 (halves agg1 write +
// gemm2 read), hist int4-vectorized.
// ---------------------------------------------------------------------------

__global__ __launch_bounds__(256) void hist_kernel(const int* __restrict__ dst, int E,
                                                   int* __restrict__ deg) {
    int i = (blockIdx.x * 256 + threadIdx.x) * 4;
    if (i + 3 < E) {
        int4 d = *(const int4*)(dst + i);
        atomicAdd(&deg[d.x], 1);
        atomicAdd(&deg[d.y], 1);
        atomicAdd(&deg[d.z], 1);
        atomicAdd(&deg[d.w], 1);
    } else {
        for (int k = i; k < E; k++) atomicAdd(&deg[dst[k]], 1);
    }
}

__global__ __launch_bounds__(256) void scan1_kernel(const int* __restrict__ deg, int N,
                                                    int* __restrict__ rowstart,
                                                    int* __restrict__ blocksum) {
    __shared__ int tmp[256];
    int t = threadIdx.x;
    int i = blockIdx.x * 256 + t;
    int v = (i < N) ? deg[i] : 0;
    tmp[t] = v;
    __syncthreads();
    for (int off = 1; off < 256; off <<= 1) {
        int x = (t >= off) ? tmp[t - off] : 0;
        __syncthreads();
        tmp[t] += x;
        __syncthreads();
    }
    if (i < N) rowstart[i] = tmp[t] - v;
    if (t == 255) blocksum[blockIdx.x] = tmp[t];
}

__global__ __launch_bounds__(256) void scan2_kernel(int* __restrict__ blocksum, int nb) {
    __shared__ int tmp[256];
    int t = threadIdx.x;
    int v = (t < nb) ? blocksum[t] : 0;
    tmp[t] = v;
    __syncthreads();
    for (int off = 1; off < 256; off <<= 1) {
        int x = (t >= off) ? tmp[t - off] : 0;
        __syncthreads();
        tmp[t] += x;
        __syncthreads();
    }
    if (t < nb) blocksum[t] = tmp[t] - v;
}

__global__ __launch_bounds__(256) void scan3_kernel(int* __restrict__ rowstart,
                                                    const int* __restrict__ blockoff,
                                                    int* __restrict__ cursor,
                                                    int N, int E) {
    int i = blockIdx.x * 256 + threadIdx.x;
    if (i < N) {
        int v = rowstart[i] + blockoff[i >> 8];
        rowstart[i] = v;
        cursor[i] = v;
    } else if (i == N) {
        rowstart[N] = E;
    }
}

// Bucketed scatter: block (blockIdx&7) commits only dst in its 1/8 range of
// nodes -> esrc write lines stay within one XCD's L2 (round-robin dispatch).
__global__ __launch_bounds__(256) void scatter_kernel(const int* __restrict__ src,
                                                      const int* __restrict__ dst,
                                                      int E, int N,
                                                      int* __restrict__ cursor,
                                                      int* __restrict__ esrc) {
    int b = blockIdx.x & 7;
    int chunk = blockIdx.x >> 3;
    int bdiv = (N + 7) >> 3;
    int blo = b * bdiv;
    int bhi = blo + bdiv;
    int base = chunk * 1024 + threadIdx.x;
#pragma unroll
    for (int u = 0; u < 4; u++) {
        int i = base + u * 256;
        if (i < E) {
            int d = dst[i];
            int s = src[i];
            if (d >= blo && d < bhi) {
                int p = atomicAdd(&cursor[d], 1);
                esrc[p] = s;
            }
        }
    }
}

// GEMM1: h1[N,128] = x[N,128] @ W1[128,128] (fp16 out). 32-row tile, thread
// owns 4 rows x 4 cols. Epilogue: per-head alpha dots via 4-lane shuffle.
__global__ __launch_bounds__(256) void gemm1_kernel(const float* __restrict__ x,
                                                    const float* __restrict__ W,
                                                    const float* __restrict__ a_s,
                                                    const float* __restrict__ a_d,
                                                    __half* __restrict__ h1,
                                                    float* __restrict__ als,
                                                    float* __restrict__ ald, int N) {
    __shared__ float Xs[32 * 128];
    __shared__ float Ws[32 * 128];
    int t = threadIdx.x;
    int row0 = blockIdx.x * 32;
    int cg = t & 31;
    int rg = t >> 5;
    {
        const float4* xv = (const float4*)(x + (size_t)row0 * 128);
        float4* Xv = (float4*)Xs;
        int valid = (N - row0) * 32;
        for (int i = t; i < 1024; i += 256)
            Xv[i] = (i < valid) ? xv[i] : make_float4(0.f, 0.f, 0.f, 0.f);
    }
    float acc[4][4];
#pragma unroll
    for (int i = 0; i < 4; i++)
#pragma unroll
        for (int j = 0; j < 4; j++) acc[i][j] = 0.f;

    for (int kt = 0; kt < 4; kt++) {
        __syncthreads();
        {
            const float4* wv = (const float4*)(W + (size_t)kt * 32 * 128);
            float4* Wv = (float4*)Ws;
            for (int i = t; i < 1024; i += 256) Wv[i] = wv[i];
        }
        __syncthreads();
        const float* xb = Xs + (size_t)rg * 4 * 128 + kt * 32;
#pragma unroll 8
        for (int kk = 0; kk < 32; kk++) {
            float4 w = *(const float4*)(Ws + kk * 128 + cg * 4);
            float x0 = xb[kk];
            float x1 = xb[128 + kk];
            float x2 = xb[256 + kk];
            float x3 = xb[384 + kk];
            acc[0][0] += x0 * w.x; acc[0][1] += x0 * w.y; acc[0][2] += x0 * w.z; acc[0][3] += x0 * w.w;
            acc[1][0] += x1 * w.x; acc[1][1] += x1 * w.y; acc[1][2] += x1 * w.z; acc[1][3] += x1 * w.w;
            acc[2][0] += x2 * w.x; acc[2][1] += x2 * w.y; acc[2][2] += x2 * w.z; acc[2][3] += x2 * w.w;
            acc[3][0] += x3 * w.x; acc[3][1] += x3 * w.y; acc[3][2] += x3 * w.z; acc[3][3] += x3 * w.w;
        }
    }
    int head = cg >> 2;
    int abase = head * 16 + (cg & 3) * 4;
    float as0 = a_s[abase], as1 = a_s[abase + 1], as2 = a_s[abase + 2], as3 = a_s[abase + 3];
    float ad0 = a_d[abase], ad1 = a_d[abase + 1], ad2 = a_d[abase + 2], ad3 = a_d[abase + 3];
#pragma unroll
    for (int i = 0; i < 4; i++) {
        int n = row0 + rg * 4 + i;
        if (n < N) {
            __align__(8) __half2 pk[2];
            pk[0] = __floats2half2_rn(acc[i][0], acc[i][1]);
            pk[1] = __floats2half2_rn(acc[i][2], acc[i][3]);
            *(float2*)(h1 + (size_t)n * 128 + cg * 4) = *(float2*)pk;
            float ds = acc[i][0] * as0 + acc[i][1] * as1 + acc[i][2] * as2 + acc[i][3] * as3;
            float dd = acc[i][0] * ad0 + acc[i][1] * ad1 + acc[i][2] * ad2 + acc[i][3] * ad3;
            ds += __shfl_xor(ds, 1, 64); ds += __shfl_xor(ds, 2, 64);
            dd += __shfl_xor(dd, 1, 64); dd += __shfl_xor(dd, 2, 64);
            if ((cg & 3) == 0) {
                als[n * 8 + head] = ds;
                ald[n * 8 + head] = dd;
            }
        }
    }
}

// Aggregation layer 1: one wave per dst node, 8 groups of 8 lanes; group g
// processes edges beg+g, beg+g+8, ... Lane q (=lane&7) owns head q's 16
// channels. Hot loop: packed __hfma2 into fp16 accumulators (few edges per
// group); converted to fp32 before cross-group reduce + self-loop + epilogue.
__global__ __launch_bounds__(256) void agg1_kernel(const __half* __restrict__ h1,
                                                   const float* __restrict__ als,
                                                   const float* __restrict__ ald,
                                                   const int* __restrict__ rowstart,
                                                   const int* __restrict__ esrc,
                                                   const float* __restrict__ b1,
                                                   __half* __restrict__ act1, int N) {
    int gtid = blockIdx.x * 256 + threadIdx.x;
    int n = gtid >> 6;
    if (n >= N) return;
    int lane = threadIdx.x & 63;
    int grp = lane >> 3;
    int q = lane & 7;        // head q, channels 16q..16q+15
    const float4* h1v = (const float4*)h1;  // 16 float4 per row
    float adv = ald[n * 8 + q];
    __half2 acc2[8];
#pragma unroll
    for (int k = 0; k < 8; k++) acc2[k] = __half2half2(__float2half(0.f));
    float wsum = 0.f;
    int beg = rowstart[n], end = rowstart[n + 1];
    for (int j = beg + grp; j < end; j += 8) {
        int s = esrc[j];
        float e = als[s * 8 + q] + adv;
        e = (e > 0.f) ? e : 0.2f * e;
        float w = __expf(e);
        wsum += w;
        __half2 wh = __float2half2_rn(w);
        float4 hv0 = h1v[(size_t)s * 16 + 2 * q];
        float4 hv1 = h1v[(size_t)s * 16 + 2 * q + 1];
        const __half2* p0 = (const __half2*)&hv0;
        const __half2* p1 = (const __half2*)&hv1;
        acc2[0] = __hfma2(wh, p0[0], acc2[0]);
        acc2[1] = __hfma2(wh, p0[1], acc2[1]);
        acc2[2] = __hfma2(wh, p0[2], acc2[2]);
        acc2[3] = __hfma2(wh, p0[3], acc2[3]);
        acc2[4] = __hfma2(wh, p1[0], acc2[4]);
        acc2[5] = __hfma2(wh, p1[1], acc2[5]);
        acc2[6] = __hfma2(wh, p1[2], acc2[6]);
        acc2[7] = __hfma2(wh, p1[3], acc2[7]);
    }
    float acc[16];
#pragma unroll
    for (int k = 0; k < 8; k++) {
        float2 f = __half22float2(acc2[k]);
        acc[2 * k] = f.x;
        acc[2 * k + 1] = f.y;
    }
#pragma unroll
    for (int off = 8; off < 64; off <<= 1) {
        wsum += __shfl_xor(wsum, off, 64);
#pragma unroll
        for (int k = 0; k < 16; k++) acc[k] += __shfl_xor(acc[k], off, 64);
    }
    {  // self loop in fp32 (once)
        float e = als[n * 8 + q] + adv;
        e = (e > 0.f) ? e : 0.2f * e;
        float w = __expf(e);
        wsum += w;
        float4 hv0 = h1v[(size_t)n * 16 + 2 * q];
        float4 hv1 = h1v[(size_t)n * 16 + 2 * q + 1];
        const __half2* p0 = (const __half2*)&hv0;
        const __half2* p1 = (const __half2*)&hv1;
#pragma unroll
        for (int k = 0; k < 4; k++) {
            float2 f = __half22float2(p0[k]);
            acc[2 * k] += w * f.x;
            acc[2 * k + 1] += w * f.y;
        }
#pragma unroll
        for (int k = 0; k < 4; k++) {
            float2 f = __half22float2(p1[k]);
            acc[8 + 2 * k] += w * f.x;
            acc[8 + 2 * k + 1] += w * f.y;
        }
    }
    if (grp == 0) {
        float inv = 1.f / (wsum + 1e-16f);
        __align__(16) __half2 po[8];
#pragma unroll
        for (int k = 0; k < 8; k++) {
            float o0 = acc[2 * k] * inv + b1[q * 16 + 2 * k];
            float o1 = acc[2 * k + 1] * inv + b1[q * 16 + 2 * k + 1];
            o0 = (o0 > 0.f) ? o0 : (__expf(o0) - 1.f);  // ELU
            o1 = (o1 > 0.f) ? o1 : (__expf(o1) - 1.f);
            po[k] = __floats2half2_rn(o0, o1);
        }
        float4* ov = (float4*)(act1 + (size_t)n * 128 + q * 16);
        ov[0] = ((float4*)po)[0];
        ov[1] = ((float4*)po)[1];
    }
}

// GEMM2: h2[N,64] = act1[N,128](fp16) @ W2[128,64] (fp16 out). 64-row tile,
// thread owns 4 rows x 4 cols; act1 converted to fp32 while staging into LDS.
__global__ __launch_bounds__(256) void gemm2_kernel(const __half* __restrict__ act1,
                                                    const float* __restrict__ W2,
                                                    const float* __restrict__ a2s,
                                                    const float* __restrict__ a2d,
                                                    __half* __restrict__ h2,
                                                    float* __restrict__ al2s,
                                                    float* __restrict__ al2d, int N) {
    __shared__ float Ws[128 * 64];
    __shared__ float Xs[64 * 128];
    int t = threadIdx.x;
    int row0 = blockIdx.x * 64;
    int cg = t & 15;
    int rg = t >> 4;
    {
        const float4* wv = (const float4*)W2;
        float4* Wv = (float4*)Ws;
        for (int i = t; i < 2048; i += 256) Wv[i] = wv[i];
    }
    {
        const float2* xv = (const float2*)(act1 + (size_t)row0 * 128);  // 4 halves
        float4* Xv = (float4*)Xs;
        int valid = (N - row0) * 32;
        for (int i = t; i < 2048; i += 256) {
            float2 raw = (i < valid) ? xv[i] : make_float2(0.f, 0.f);
            const __half2* hp = (const __half2*)&raw;
            float2 f0 = __half22float2(hp[0]);
            float2 f1 = __half22float2(hp[1]);
            Xv[i] = make_float4(f0.x, f0.y, f1.x, f1.y);
        }
    }
    __syncthreads();
    float acc[4][4];
#pragma unroll
    for (int i = 0; i < 4; i++)
#pragma unroll
        for (int j = 0; j < 4; j++) acc[i][j] = 0.f;
    const float* xb = Xs + (size_t)rg * 4 * 128;
#pragma unroll 8
    for (int k = 0; k < 128; k++) {
        float4 w = *(const float4*)(Ws + k * 64 + cg * 4);
        float x0 = xb[k];
        float x1 = xb[128 + k];
        float x2 = xb[256 + k];
        float x3 = xb[384 + k];
        acc[0][0] += x0 * w.x; acc[0][1] += x0 * w.y; acc[0][2] += x0 * w.z; acc[0][3] += x0 * w.w;
        acc[1][0] += x1 * w.x; acc[1][1] += x1 * w.y; acc[1][2] += x1 * w.z; acc[1][3] += x1 * w.w;
        acc[2][0] += x2 * w.x; acc[2][1] += x2 * w.y; acc[2][2] += x2 * w.z; acc[2][3] += x2 * w.w;
        acc[3][0] += x3 * w.x; acc[3][1] += x3 * w.y; acc[3][2] += x3 * w.z; acc[3][3] += x3 * w.w;
    }
    float as0 = a2s[cg * 4], as1 = a2s[cg * 4 + 1], as2 = a2s[cg * 4 + 2], as3 = a2s[cg * 4 + 3];
    float ad0 = a2d[cg * 4], ad1 = a2d[cg * 4 + 1], ad2 = a2d[cg * 4 + 2], ad3 = a2d[cg * 4 + 3];
#pragma unroll
    for (int i = 0; i < 4; i++) {
        int n = row0 + rg * 4 + i;
        if (n < N) {
            __align__(8) __half2 pk[2];
            pk[0] = __floats2half2_rn(acc[i][0], acc[i][1]);
            pk[1] = __floats2half2_rn(acc[i][2], acc[i][3]);
            *(float2*)(h2 + (size_t)n * 64 + cg * 4) = *(float2*)pk;
            float ps = acc[i][0] * as0 + acc[i][1] * as1 + acc[i][2] * as2 + acc[i][3] * as3;
            float pd = acc[i][0] * ad0 + acc[i][1] * ad1 + acc[i][2] * ad2 + acc[i][3] * ad3;
#pragma unroll
            for (int off = 1; off < 16; off <<= 1) {
                ps += __shfl_xor(ps, off, 64);
                pd += __shfl_xor(pd, off, 64);
            }
            if (cg == 0) {
                al2s[n] = ps;
                al2d[n] = pd;
            }
        }
    }
}

// Aggregation layer 2: wave per node, 8 groups of 8 lanes; lane q owns
// channels 8q..8q+7. Packed __hfma2 accumulation; fp32 reduce + epilogue.
__global__ __launch_bounds__(256) void agg2_kernel(const __half* __restrict__ h2,
                                                   const float* __restrict__ al2s,
                                                   const float* __restrict__ al2d,
                                                   const int* __restrict__ rowstart,
                                                   const int* __restrict__ esrc,
                                                   const float* __restrict__ b2,
                                                   float* __restrict__ out, int N) {
    int gtid = blockIdx.x * 256 + threadIdx.x;
    int n = gtid >> 6;
    if (n >= N) return;
    int lane = threadIdx.x & 63;
    int grp = lane >> 3;
    int q = lane & 7;  // channels 8q..8q+7
    const float4* h2v = (const float4*)h2;  // 8 float4 per row
    float adv = al2d[n];
    __half2 acc2[4];
#pragma unroll
    for (int k = 0; k < 4; k++) acc2[k] = __half2half2(__float2half(0.f));
    float wsum = 0.f;
    int beg = rowstart[n], end = rowstart[n + 1];
    for (int j = beg + grp; j < end; j += 8) {
        int s = esrc[j];
        float e = al2s[s] + adv;
        e = (e > 0.f) ? e : 0.2f * e;
        float w = __expf(e);
        wsum += w;
        __half2 wh = __float2half2_rn(w);
        float4 hv = h2v[(size_t)s * 8 + q];
        const __half2* hp = (const __half2*)&hv;
        acc2[0] = __hfma2(wh, hp[0], acc2[0]);
        acc2[1] = __hfma2(wh, hp[1], acc2[1]);
        acc2[2] = __hfma2(wh, hp[2], acc2[2]);
        acc2[3] = __hfma2(wh, hp[3], acc2[3]);
    }
    float acc[8];
#pragma unroll
    for (int k = 0; k < 4; k++) {
        float2 f = __half22float2(acc2[k]);
        acc[2 * k] = f.x;
        acc[2 * k + 1] = f.y;
    }
#pragma unroll
    for (int off = 8; off < 64; off <<= 1) {
        wsum += __shfl_xor(wsum, off, 64);
#pragma unroll
        for (int k = 0; k < 8; k++) acc[k] += __shfl_xor(acc[k], off, 64);
    }
    {  // self loop in fp32 (once)
        float e = al2s[n] + adv;
        e = (e > 0.f) ? e : 0.2f * e;
        float w = __expf(e);
        wsum += w;
        float4 hv = h2v[(size_t)n * 8 + q];
        const __half2* hp = (const __half2*)&hv;
#pragma unroll
        for (int k = 0; k < 4; k++) {
            float2 f = __half22float2(hp[k]);
            acc[2 * k] += w * f.x;
            acc[2 * k + 1] += w * f.y;
        }
    }
    if (grp == 0) {
        float inv = 1.f / (wsum + 1e-16f);
        float4* ov = (float4*)(out + (size_t)n * 64 + q * 8);
        ov[0] = make_float4(acc[0] * inv + b2[q * 8],
                            acc[1] * inv + b2[q * 8 + 1],
                            acc[2] * inv + b2[q * 8 + 2],
                            acc[3] * inv + b2[q * 8 + 3]);
        ov[1] = make_float4(acc[4] * inv + b2[q * 8 + 4],
                            acc[5] * inv + b2[q * 8 + 5],
                            acc[6] * inv + b2[q * 8 + 6],
                            acc[7] * inv + b2[q * 8 + 7]);
    }
}

extern "C" void kernel_launch(void* const* d_in, const int* in_sizes, int n_in,
                              void* d_out, int out_size, void* d_ws, size_t ws_size,
                              hipStream_t stream) {
    (void)n_in; (void)out_size; (void)ws_size;
    const float* x   = (const float*)d_in[0];
    const int*   ei  = (const int*)d_in[1];
    const float* W1  = (const float*)d_in[2];
    const float* a1s = (const float*)d_in[3];
    const float* a1d = (const float*)d_in[4];
    const float* b1  = (const float*)d_in[5];
    const float* W2  = (const float*)d_in[6];
    const float* a2s = (const float*)d_in[7];
    const float* a2d = (const float*)d_in[8];
    const float* b2  = (const float*)d_in[9];
    float* out = (float*)d_out;

    const int N = in_sizes[0] / 128;
    const int E = in_sizes[1] / 2;
    const int* src = ei;
    const int* dst = ei + E;

    char* wp = (char*)d_ws;
    auto alloc = [&](size_t bytes) -> void* {
        void* p = (void*)wp;
        wp += (bytes + 255) & ~(size_t)255;
        return p;
    };
    __half* h1   = (__half*)alloc((size_t)N * 128 * 2);
    __half* act1 = (__half*)alloc((size_t)N * 128 * 2);
    __half* h2   = (__half*)alloc((size_t)N * 64 * 2);
    float* al1s = (float*)alloc((size_t)N * 8 * 4);
    float* al1d = (float*)alloc((size_t)N * 8 * 4);
    float* al2s = (float*)alloc((size_t)N * 4);
    float* al2d = (float*)alloc((size_t)N * 4);
    int* deg      = (int*)alloc((size_t)N * 4);
    int* rowstart = (int*)alloc((size_t)(N + 1) * 4);
    int* cursor   = (int*)alloc((size_t)N * 4);
    int* esrc     = (int*)alloc((size_t)E * 4);
    int* blocksum = (int*)alloc(256 * 4);

    const int nbScan = (N + 255) / 256;
    const int gridH  = (E + 1023) / 1024;
    const int gridScat = ((E + 1023) / 1024) * 8;
    const int gridG1 = (N + 31) / 32;
    const int gridG2 = (N + 63) / 64;
    const int gridAgg = (N * 64 + 255) / 256;

    hipMemsetAsync(deg, 0, (size_t)N * 4, stream);

    hist_kernel<<<gridH, 256, 0, stream>>>(dst, E, deg);
    scan1_kernel<<<nbScan, 256, 0, stream>>>(deg, N, rowstart, blocksum);
    scan2_kernel<<<1, 256, 0, stream>>>(blocksum, nbScan);
    scan3_kernel<<<(N + 256) / 256, 256, 0, stream>>>(rowstart, blocksum, cursor, N, E);
    scatter_kernel<<<gridScat, 256, 0, stream>>>(src, dst, E, N, cursor, esrc);

    gemm1_kernel<<<gridG1, 256, 0, stream>>>(x, W1, a1s, a1d, h1, al1s, al1d, N);
    agg1_kernel<<<gridAgg, 256, 0, stream>>>(h1, al1s, al1d, rowstart, esrc, b1, act1, N);
    gemm2_kernel<<<gridG2, 256, 0, stream>>>(act1, W2, a2s, a2d, h2, al2s, al2d, N);
    agg2_kernel<<<gridAgg, 256, 0, stream>>>(h2, al2s, al2d, rowstart, esrc, b2, out, N);
}

// Round 7
// 277.179 us; speedup vs baseline: 1.6398x; 1.0357x over previous
//
#include <hip/hip_runtime.h>
#include <hip/hip_fp16.h>
#include <math.h>

// ---------------------------------------------------------------------------
// GAT 2-layer forward, N=50000, E=800000 (+N self loops), EMB=128,
// layer1: heads=8, C=16 (concat -> 128), layer2: heads=1, C=64.
// CSR-by-dst build per call, fused GEMM+alpha epilogues, one gather pass per
// layer, softmax without max-subtraction. h1/h2/act1 in fp16.
// R6: agg kernels node-per-group (8 nodes/wave, 8 lanes each, lane owns one
//     head) -> zero cross-group reduction; hist fused into gemm1; scan2+scan3
//     merged. R7: fix UB in agg1 epilogue (casting &float4 local to float*
//     and reading 16 floats) -> read b1 directly.
// ---------------------------------------------------------------------------

__global__ __launch_bounds__(256) void scan1_kernel(const int* __restrict__ deg, int N,
                                                    int* __restrict__ rowstart,
                                                    int* __restrict__ blocksum) {
    __shared__ int tmp[256];
    int t = threadIdx.x;
    int i = blockIdx.x * 256 + t;
    int v = (i < N) ? deg[i] : 0;
    tmp[t] = v;
    __syncthreads();
    for (int off = 1; off < 256; off <<= 1) {
        int x = (t >= off) ? tmp[t - off] : 0;
        __syncthreads();
        tmp[t] += x;
        __syncthreads();
    }
    if (i < N) rowstart[i] = tmp[t] - v;
    if (t == 255) blocksum[blockIdx.x] = tmp[t];
}

// Fused scan2+scan3: block b computes offset = sum(blocksum[0..b-1]) via a
// masked LDS reduce (nb<=256), then adds it to its rowstart slice and
// initializes cursor.
__global__ __launch_bounds__(256) void scan23_kernel(int* __restrict__ rowstart,
                                                     const int* __restrict__ blocksum,
                                                     int nb,
                                                     int* __restrict__ cursor,
                                                     int N, int E) {
    __shared__ int sdata[256];
    int t = threadIdx.x;
    int b = blockIdx.x;
    sdata[t] = (t < nb && t < b) ? blocksum[t] : 0;
    __syncthreads();
#pragma unroll
    for (int off = 128; off > 0; off >>= 1) {
        if (t < off) sdata[t] += sdata[t + off];
        __syncthreads();
    }
    int offset = sdata[0];
    int i = b * 256 + t;
    if (i < N) {
        int v = rowstart[i] + offset;
        rowstart[i] = v;
        cursor[i] = v;
    } else if (i == N) {
        rowstart[N] = E;
    }
}

// Bucketed scatter: block (blockIdx&7) commits only dst in its 1/8 range of
// nodes -> esrc write lines stay within one XCD's L2 (round-robin dispatch).
__global__ __launch_bounds__(256) void scatter_kernel(const int* __restrict__ src,
                                                      const int* __restrict__ dst,
                                                      int E, int N,
                                                      int* __restrict__ cursor,
                                                      int* __restrict__ esrc) {
    int b = blockIdx.x & 7;
    int chunk = blockIdx.x >> 3;
    int bdiv = (N + 7) >> 3;
    int blo = b * bdiv;
    int bhi = blo + bdiv;
    int base = chunk * 1024 + threadIdx.x;
#pragma unroll
    for (int u = 0; u < 4; u++) {
        int i = base + u * 256;
        if (i < E) {
            int d = dst[i];
            int s = src[i];
            if (d >= blo && d < bhi) {
                int p = atomicAdd(&cursor[d], 1);
                esrc[p] = s;
            }
        }
    }
}

// Fat kernel: blocks [0,G1) run GEMM1 (h1 = x @ W1, fp16 out + per-head alpha
// dots); blocks [G1, G1+GH) run the edge histogram (hides under the GEMM).
__global__ __launch_bounds__(256) void gemm1_hist_kernel(const float* __restrict__ x,
                                                         const float* __restrict__ W,
                                                         const float* __restrict__ a_s,
                                                         const float* __restrict__ a_d,
                                                         __half* __restrict__ h1,
                                                         float* __restrict__ als,
                                                         float* __restrict__ ald, int N,
                                                         const int* __restrict__ dst,
                                                         int E, int* __restrict__ deg,
                                                         int G1) {
    if ((int)blockIdx.x >= G1) {  // ---- histogram part ----
        int hb = blockIdx.x - G1;
        int i = (hb * 256 + threadIdx.x) * 4;
        if (i + 3 < E) {
            int4 d = *(const int4*)(dst + i);
            atomicAdd(&deg[d.x], 1);
            atomicAdd(&deg[d.y], 1);
            atomicAdd(&deg[d.z], 1);
            atomicAdd(&deg[d.w], 1);
        } else {
            for (int k = i; k < E; k++) atomicAdd(&deg[dst[k]], 1);
        }
        return;
    }
    // ---- GEMM1 part: 32-row tile, thread owns 4 rows x 4 cols ----
    __shared__ float Xs[32 * 128];
    __shared__ float Ws[32 * 128];
    int t = threadIdx.x;
    int row0 = blockIdx.x * 32;
    int cg = t & 31;
    int rg = t >> 5;
    {
        const float4* xv = (const float4*)(x + (size_t)row0 * 128);
        float4* Xv = (float4*)Xs;
        int valid = (N - row0) * 32;
        for (int i = t; i < 1024; i += 256)
            Xv[i] = (i < valid) ? xv[i] : make_float4(0.f, 0.f, 0.f, 0.f);
    }
    float acc[4][4];
#pragma unroll
    for (int i = 0; i < 4; i++)
#pragma unroll
        for (int j = 0; j < 4; j++) acc[i][j] = 0.f;

    for (int kt = 0; kt < 4; kt++) {
        __syncthreads();
        {
            const float4* wv = (const float4*)(W + (size_t)kt * 32 * 128);
            float4* Wv = (float4*)Ws;
            for (int i = t; i < 1024; i += 256) Wv[i] = wv[i];
        }
        __syncthreads();
        const float* xb = Xs + (size_t)rg * 4 * 128 + kt * 32;
#pragma unroll 8
        for (int kk = 0; kk < 32; kk++) {
            float4 w = *(const float4*)(Ws + kk * 128 + cg * 4);
            float x0 = xb[kk];
            float x1 = xb[128 + kk];
            float x2 = xb[256 + kk];
            float x3 = xb[384 + kk];
            acc[0][0] += x0 * w.x; acc[0][1] += x0 * w.y; acc[0][2] += x0 * w.z; acc[0][3] += x0 * w.w;
            acc[1][0] += x1 * w.x; acc[1][1] += x1 * w.y; acc[1][2] += x1 * w.z; acc[1][3] += x1 * w.w;
            acc[2][0] += x2 * w.x; acc[2][1] += x2 * w.y; acc[2][2] += x2 * w.z; acc[2][3] += x2 * w.w;
            acc[3][0] += x3 * w.x; acc[3][1] += x3 * w.y; acc[3][2] += x3 * w.z; acc[3][3] += x3 * w.w;
        }
    }
    int head = cg >> 2;
    int abase = head * 16 + (cg & 3) * 4;
    float as0 = a_s[abase], as1 = a_s[abase + 1], as2 = a_s[abase + 2], as3 = a_s[abase + 3];
    float ad0 = a_d[abase], ad1 = a_d[abase + 1], ad2 = a_d[abase + 2], ad3 = a_d[abase + 3];
#pragma unroll
    for (int i = 0; i < 4; i++) {
        int n = row0 + rg * 4 + i;
        if (n < N) {
            __align__(8) __half2 pk[2];
            pk[0] = __floats2half2_rn(acc[i][0], acc[i][1]);
            pk[1] = __floats2half2_rn(acc[i][2], acc[i][3]);
            *(float2*)(h1 + (size_t)n * 128 + cg * 4) = *(float2*)pk;
            float ds = acc[i][0] * as0 + acc[i][1] * as1 + acc[i][2] * as2 + acc[i][3] * as3;
            float dd = acc[i][0] * ad0 + acc[i][1] * ad1 + acc[i][2] * ad2 + acc[i][3] * ad3;
            ds += __shfl_xor(ds, 1, 64); ds += __shfl_xor(ds, 2, 64);
            dd += __shfl_xor(dd, 1, 64); dd += __shfl_xor(dd, 2, 64);
            if ((cg & 3) == 0) {
                als[n * 8 + head] = ds;
                ald[n * 8 + head] = dd;
            }
        }
    }
}

// Aggregation layer 1, node-per-group: wave = 8 nodes x 8 lanes. Lane q of
// group g owns head q's 16 channels of node (base+g) and walks that node's
// whole edge list privately -> per-head softmax per-lane, NO cross-lane
// reduction. fp32 accumulate. Epilogue: +b1, ELU, fp16 store.
__global__ __launch_bounds__(256) void agg1_kernel(const __half* __restrict__ h1,
                                                   const float* __restrict__ als,
                                                   const float* __restrict__ ald,
                                                   const int* __restrict__ rowstart,
                                                   const int* __restrict__ esrc,
                                                   const float* __restrict__ b1,
                                                   __half* __restrict__ act1, int N) {
    int t = threadIdx.x;
    int lane = t & 63;
    int grp = lane >> 3;
    int q = lane & 7;  // head q, channels 16q..16q+15
    int n = blockIdx.x * 32 + (t >> 6) * 8 + grp;
    if (n >= N) return;
    const float4* h1v = (const float4*)h1;  // 16 float4 per row
    float adv = ald[n * 8 + q];
    float acc[16];
    float wsum;
    {  // self loop
        float e = als[n * 8 + q] + adv;
        e = (e > 0.f) ? e : 0.2f * e;
        float w = __expf(e);
        wsum = w;
        float4 hv0 = h1v[(size_t)n * 16 + 2 * q];
        float4 hv1 = h1v[(size_t)n * 16 + 2 * q + 1];
        const __half2* p0 = (const __half2*)&hv0;
        const __half2* p1 = (const __half2*)&hv1;
#pragma unroll
        for (int k = 0; k < 4; k++) {
            float2 f = __half22float2(p0[k]);
            acc[2 * k] = w * f.x;
            acc[2 * k + 1] = w * f.y;
        }
#pragma unroll
        for (int k = 0; k < 4; k++) {
            float2 f = __half22float2(p1[k]);
            acc[8 + 2 * k] = w * f.x;
            acc[8 + 2 * k + 1] = w * f.y;
        }
    }
    int beg = rowstart[n], end = rowstart[n + 1];
    for (int j = beg; j < end; j++) {
        int s = esrc[j];
        float e = als[s * 8 + q] + adv;
        e = (e > 0.f) ? e : 0.2f * e;
        float w = __expf(e);
        wsum += w;
        float4 hv0 = h1v[(size_t)s * 16 + 2 * q];
        float4 hv1 = h1v[(size_t)s * 16 + 2 * q + 1];
        const __half2* p0 = (const __half2*)&hv0;
        const __half2* p1 = (const __half2*)&hv1;
#pragma unroll
        for (int k = 0; k < 4; k++) {
            float2 f = __half22float2(p0[k]);
            acc[2 * k] += w * f.x;
            acc[2 * k + 1] += w * f.y;
        }
#pragma unroll
        for (int k = 0; k < 4; k++) {
            float2 f = __half22float2(p1[k]);
            acc[8 + 2 * k] += w * f.x;
            acc[8 + 2 * k + 1] += w * f.y;
        }
    }
    float inv = 1.f / (wsum + 1e-16f);
    const float* bf = b1 + q * 16;  // R7 fix: direct reads (L1-resident)
    __align__(16) __half2 po[8];
#pragma unroll
    for (int k = 0; k < 8; k++) {
        float o0 = acc[2 * k] * inv + bf[2 * k];
        float o1 = acc[2 * k + 1] * inv + bf[2 * k + 1];
        o0 = (o0 > 0.f) ? o0 : (__expf(o0) - 1.f);  // ELU
        o1 = (o1 > 0.f) ? o1 : (__expf(o1) - 1.f);
        po[k] = __floats2half2_rn(o0, o1);
    }
    float4* ov = (float4*)(act1 + (size_t)n * 128 + q * 16);
    ov[0] = ((float4*)po)[0];
    ov[1] = ((float4*)po)[1];
}

// GEMM2: h2[N,64] = act1[N,128](fp16) @ W2[128,64] (fp16 out). 64-row tile,
// thread owns 4 rows x 4 cols; act1 converted to fp32 while staging into LDS.
__global__ __launch_bounds__(256) void gemm2_kernel(const __half* __restrict__ act1,
                                                    const float* __restrict__ W2,
                                                    const float* __restrict__ a2s,
                                                    const float* __restrict__ a2d,
                                                    __half* __restrict__ h2,
                                                    float* __restrict__ al2s,
                                                    float* __restrict__ al2d, int N) {
    __shared__ float Ws[128 * 64];
    __shared__ float Xs[64 * 128];
    int t = threadIdx.x;
    int row0 = blockIdx.x * 64;
    int cg = t & 15;
    int rg = t >> 4;
    {
        const float4* wv = (const float4*)W2;
        float4* Wv = (float4*)Ws;
        for (int i = t; i < 2048; i += 256) Wv[i] = wv[i];
    }
    {
        const float2* xv = (const float2*)(act1 + (size_t)row0 * 128);  // 4 halves
        float4* Xv = (float4*)Xs;
        int valid = (N - row0) * 32;
        for (int i = t; i < 2048; i += 256) {
            float2 raw = (i < valid) ? xv[i] : make_float2(0.f, 0.f);
            const __half2* hp = (const __half2*)&raw;
            float2 f0 = __half22float2(hp[0]);
            float2 f1 = __half22float2(hp[1]);
            Xv[i] = make_float4(f0.x, f0.y, f1.x, f1.y);
        }
    }
    __syncthreads();
    float acc[4][4];
#pragma unroll
    for (int i = 0; i < 4; i++)
#pragma unroll
        for (int j = 0; j < 4; j++) acc[i][j] = 0.f;
    const float* xb = Xs + (size_t)rg * 4 * 128;
#pragma unroll 8
    for (int k = 0; k < 128; k++) {
        float4 w = *(const float4*)(Ws + k * 64 + cg * 4);
        float x0 = xb[k];
        float x1 = xb[128 + k];
        float x2 = xb[256 + k];
        float x3 = xb[384 + k];
        acc[0][0] += x0 * w.x; acc[0][1] += x0 * w.y; acc[0][2] += x0 * w.z; acc[0][3] += x0 * w.w;
        acc[1][0] += x1 * w.x; acc[1][1] += x1 * w.y; acc[1][2] += x1 * w.z; acc[1][3] += x1 * w.w;
        acc[2][0] += x2 * w.x; acc[2][1] += x2 * w.y; acc[2][2] += x2 * w.z; acc[2][3] += x2 * w.w;
        acc[3][0] += x3 * w.x; acc[3][1] += x3 * w.y; acc[3][2] += x3 * w.z; acc[3][3] += x3 * w.w;
    }
    float as0 = a2s[cg * 4], as1 = a2s[cg * 4 + 1], as2 = a2s[cg * 4 + 2], as3 = a2s[cg * 4 + 3];
    float ad0 = a2d[cg * 4], ad1 = a2d[cg * 4 + 1], ad2 = a2d[cg * 4 + 2], ad3 = a2d[cg * 4 + 3];
#pragma unroll
    for (int i = 0; i < 4; i++) {
        int n = row0 + rg * 4 + i;
        if (n < N) {
            __align__(8) __half2 pk[2];
            pk[0] = __floats2half2_rn(acc[i][0], acc[i][1]);
            pk[1] = __floats2half2_rn(acc[i][2], acc[i][3]);
            *(float2*)(h2 + (size_t)n * 64 + cg * 4) = *(float2*)pk;
            float ps = acc[i][0] * as0 + acc[i][1] * as1 + acc[i][2] * as2 + acc[i][3] * as3;
            float pd = acc[i][0] * ad0 + acc[i][1] * ad1 + acc[i][2] * ad2 + acc[i][3] * ad3;
#pragma unroll
            for (int off = 1; off < 16; off <<= 1) {
                ps += __shfl_xor(ps, off, 64);
                pd += __shfl_xor(pd, off, 64);
            }
            if (cg == 0) {
                al2s[n] = ps;
                al2d[n] = pd;
            }
        }
    }
}

// Aggregation layer 2, node-per-group: wave = 8 nodes x 8 lanes; lane q owns
// channels 8q..8q+7 of its group's node; walks the whole edge list privately.
__global__ __launch_bounds__(256) void agg2_kernel(const __half* __restrict__ h2,
                                                   const float* __restrict__ al2s,
                                                   const float* __restrict__ al2d,
                                                   const int* __restrict__ rowstart,
                                                   const int* __restrict__ esrc,
                                                   const float* __restrict__ b2,
                                                   float* __restrict__ out, int N) {
    int t = threadIdx.x;
    int lane = t & 63;
    int grp = lane >> 3;
    int q = lane & 7;  // channels 8q..8q+7
    int n = blockIdx.x * 32 + (t >> 6) * 8 + grp;
    if (n >= N) return;
    const float4* h2v = (const float4*)h2;  // 8 float4 per row
    float adv = al2d[n];
    float acc[8];
    float wsum;
    {  // self loop
        float e = al2s[n] + adv;
        e = (e > 0.f) ? e : 0.2f * e;
        float w = __expf(e);
        wsum = w;
        float4 hv = h2v[(size_t)n * 8 + q];
        const __half2* hp = (const __half2*)&hv;
#pragma unroll
        for (int k = 0; k < 4; k++) {
            float2 f = __half22float2(hp[k]);
            acc[2 * k] = w * f.x;
            acc[2 * k + 1] = w * f.y;
        }
    }
    int beg = rowstart[n], end = rowstart[n + 1];
    for (int j = beg; j < end; j++) {
        int s = esrc[j];
        float e = al2s[s] + adv;
        e = (e > 0.f) ? e : 0.2f * e;
        float w = __expf(e);
        wsum += w;
        float4 hv = h2v[(size_t)s * 8 + q];
        const __half2* hp = (const __half2*)&hv;
#pragma unroll
        for (int k = 0; k < 4; k++) {
            float2 f = __half22float2(hp[k]);
            acc[2 * k] += w * f.x;
            acc[2 * k + 1] += w * f.y;
        }
    }
    float inv = 1.f / (wsum + 1e-16f);
    const float* bf = b2 + q * 8;
    float4* ov = (float4*)(out + (size_t)n * 64 + q * 8);
    ov[0] = make_float4(acc[0] * inv + bf[0], acc[1] * inv + bf[1],
                        acc[2] * inv + bf[2], acc[3] * inv + bf[3]);
    ov[1] = make_float4(acc[4] * inv + bf[4], acc[5] * inv + bf[5],
                        acc[6] * inv + bf[6], acc[7] * inv + bf[7]);
}

extern "C" void kernel_launch(void* const* d_in, const int* in_sizes, int n_in,
                              void* d_out, int out_size, void* d_ws, size_t ws_size,
                              hipStream_t stream) {
    (void)n_in; (void)out_size; (void)ws_size;
    const float* x   = (const float*)d_in[0];
    const int*   ei  = (const int*)d_in[1];
    const float* W1  = (const float*)d_in[2];
    const float* a1s = (const float*)d_in[3];
    const float* a1d = (const float*)d_in[4];
    const float* b1  = (const float*)d_in[5];
    const float* W2  = (const float*)d_in[6];
    const float* a2s = (const float*)d_in[7];
    const float* a2d = (const float*)d_in[8];
    const float* b2  = (const float*)d_in[9];
    float* out = (float*)d_out;

    const int N = in_sizes[0] / 128;
    const int E = in_sizes[1] / 2;
    const int* src = ei;
    const int* dst = ei + E;

    char* wp = (char*)d_ws;
    auto alloc = [&](size_t bytes) -> void* {
        void* p = (void*)wp;
        wp += (bytes + 255) & ~(size_t)255;
        return p;
    };
    __half* h1   = (__half*)alloc((size_t)N * 128 * 2);
    __half* act1 = (__half*)alloc((size_t)N * 128 * 2);
    __half* h2   = (__half*)alloc((size_t)N * 64 * 2);
    float* al1s = (float*)alloc((size_t)N * 8 * 4);
    float* al1d = (float*)alloc((size_t)N * 8 * 4);
    float* al2s = (float*)alloc((size_t)N * 4);
    float* al2d = (float*)alloc((size_t)N * 4);
    int* deg      = (int*)alloc((size_t)N * 4);
    int* rowstart = (int*)alloc((size_t)(N + 1) * 4);
    int* cursor   = (int*)alloc((size_t)N * 4);
    int* esrc     = (int*)alloc((size_t)E * 4);
    int* blocksum = (int*)alloc(256 * 4);

    const int nbScan = (N + 255) / 256;
    const int gridG1 = (N + 31) / 32;             // gemm1 blocks
    const int gridH  = (E + 1023) / 1024;         // hist blocks (appended)
    const int gridScat = ((E + 1023) / 1024) * 8;
    const int gridG2 = (N + 63) / 64;
    const int gridAggN = (N + 31) / 32;           // 8 nodes/wave, 4 waves/block

    hipMemsetAsync(deg, 0, (size_t)N * 4, stream);

    gemm1_hist_kernel<<<gridG1 + gridH, 256, 0, stream>>>(
        x, W1, a1s, a1d, h1, al1s, al1d, N, dst, E, deg, gridG1);
    scan1_kernel<<<nbScan, 256, 0, stream>>>(deg, N, rowstart, blocksum);
    scan23_kernel<<<(N + 256) / 256, 256, 0, stream>>>(rowstart, blocksum, nbScan,
                                                       cursor, N, E);
    scatter_kernel<<<gridScat, 256, 0, stream>>>(src, dst, E, N, cursor, esrc);

    agg1_kernel<<<gridAggN, 256, 0, stream>>>(h1, al1s, al1d, rowstart, esrc, b1, act1, N);
    gemm2_kernel<<<gridG2, 256, 0, stream>>>(act1, W2, a2s, a2d, h2, al2s, al2d, N);
    agg2_kernel<<<gridAggN, 256, 0, stream>>>(h2, al2s, al2d, rowstart, esrc, b2, out, N);
}